// Round 8
// baseline (788.528 us; speedup 1.0000x reference)
//
#include <hip/hip_runtime.h>

#define FDIM 128
#define LN_EPS 1e-5f
#define NBKT_SHIFT 10          // 1024 nodes per bucket
#define BKT_NODES 1024
#define MAXBKT 128             // supports N <= 131072

typedef short bf16x8 __attribute__((ext_vector_type(8)));
typedef float f32x4 __attribute__((ext_vector_type(4)));
typedef ushort u16x8 __attribute__((ext_vector_type(8)));
typedef unsigned long long u64;

static __device__ __forceinline__ ushort f2bf(float f) {
    union { float f; unsigned u; } v; v.f = f;
    unsigned r = v.u + 0x7FFFu + ((v.u >> 16) & 1u);  // RNE
    return (ushort)(r >> 16);
}
static __device__ __forceinline__ float bf2f(ushort h) {
    union { unsigned u; float f; } v; v.u = ((unsigned)h) << 16;
    return v.f;
}

// ---------------- bucketed CSR build ----------------

__launch_bounds__(256)
__global__ void k_bkt_hist(const int* __restrict__ dst, int* __restrict__ ghist,
                           int E, int nbkt) {
    __shared__ int h[MAXBKT];
    const int t = threadIdx.x;
    for (int i = t; i < nbkt; i += 256) h[i] = 0;
    __syncthreads();
    const int E4 = E >> 2;
    const int4* d4p = (const int4*)dst;
#pragma unroll
    for (int r = 0; r < 2; r++) {
        int i4 = blockIdx.x * 512 + r * 256 + t;
        if (i4 < E4) {
            int4 d = d4p[i4];
            atomicAdd(&h[d.x >> NBKT_SHIFT], 1);
            atomicAdd(&h[d.y >> NBKT_SHIFT], 1);
            atomicAdd(&h[d.z >> NBKT_SHIFT], 1);
            atomicAdd(&h[d.w >> NBKT_SHIFT], 1);
        }
    }
    __syncthreads();
    for (int i = t; i < nbkt; i += 256) if (h[i]) atomicAdd(&ghist[i], h[i]);
}

__global__ void k_bkt_scan(const int* __restrict__ ghist, int* __restrict__ bbase,
                           int* __restrict__ bcur, int nbkt) {
    if (threadIdx.x == 0) {
        int s = 0;
        for (int b = 0; b < nbkt; b++) { bbase[b] = s; bcur[b] = s; s += ghist[b]; }
        bbase[nbkt] = s;
    }
}

__launch_bounds__(256)
__global__ void k_bkt_scatter(const int* __restrict__ src, const int* __restrict__ dst,
                              int* __restrict__ bcur, u64* __restrict__ bktA,
                              int E, int nbkt) {
    __shared__ int h[MAXBKT], lbase[MAXBKT], lcur[MAXBKT];
    const int t = threadIdx.x;
    for (int i = t; i < nbkt; i += 256) h[i] = 0;
    __syncthreads();
    const int E4 = E >> 2;
    const int4* s4p = (const int4*)src;
    const int4* d4p = (const int4*)dst;
    int4 sv[2], dv[2]; bool ok[2];
#pragma unroll
    for (int r = 0; r < 2; r++) {
        int i4 = blockIdx.x * 512 + r * 256 + t;
        ok[r] = (i4 < E4);
        if (ok[r]) {
            sv[r] = s4p[i4]; dv[r] = d4p[i4];
            atomicAdd(&h[dv[r].x >> NBKT_SHIFT], 1);
            atomicAdd(&h[dv[r].y >> NBKT_SHIFT], 1);
            atomicAdd(&h[dv[r].z >> NBKT_SHIFT], 1);
            atomicAdd(&h[dv[r].w >> NBKT_SHIFT], 1);
        }
    }
    __syncthreads();
    for (int i = t; i < nbkt; i += 256) {
        lbase[i] = h[i] ? atomicAdd(&bcur[i], h[i]) : 0;
        lcur[i] = 0;
    }
    __syncthreads();
#pragma unroll
    for (int r = 0; r < 2; r++) {
        if (!ok[r]) continue;
        int ss[4] = {sv[r].x, sv[r].y, sv[r].z, sv[r].w};
        int dd[4] = {dv[r].x, dv[r].y, dv[r].z, dv[r].w};
#pragma unroll
        for (int j = 0; j < 4; j++) {
            int b = dd[j] >> NBKT_SHIFT;
            int p = atomicAdd(&lcur[b], 1);
            bktA[(size_t)lbase[b] + p] = ((u64)(unsigned)ss[j] << 32) | (unsigned)dd[j];
        }
    }
}

// merged per-bucket: degree count -> LDS scan -> row_ptr/dinv -> CSR fill
__launch_bounds__(1024)
__global__ void k_build(const u64* __restrict__ bktA, const int* __restrict__ bbase,
                        int* __restrict__ row_ptr, float* __restrict__ dinv,
                        int* __restrict__ csr_src, int N) {
    __shared__ int cnt[BKT_NODES];
    __shared__ int scan[BKT_NODES];
    __shared__ int cur[BKT_NODES];
    const int t = threadIdx.x;
    const int b = blockIdx.x;
    const int nb = b << NBKT_SHIFT;
    cnt[t] = 0;
    __syncthreads();
    const int beg = bbase[b], end = bbase[b + 1];
    for (int i = beg + t; i < end; i += 1024)
        atomicAdd(&cnt[(int)(unsigned)bktA[i] - nb], 1);
    __syncthreads();
    int my = cnt[t];
    scan[t] = my;
    __syncthreads();
#pragma unroll
    for (int off = 1; off < 1024; off <<= 1) {
        int v = (t >= off) ? scan[t - off] : 0;
        __syncthreads();
        scan[t] += v;
        __syncthreads();
    }
    const int base = bbase[b];
    const int incl = scan[t];
    cur[t] = base + incl - my;   // exclusive start
    if (t == 0 && b == 0) row_ptr[0] = 0;
    const int n = nb + t;
    if (n < N) {
        row_ptr[n + 1] = base + incl;
        dinv[n] = rsqrtf((float)(my + 1));  // +1 self-loop
    }
    __syncthreads();
    for (int i = beg + t; i < end; i += 1024) {
        u64 pr = bktA[i];
        int d = (int)(unsigned)pr - nb;
        int p = atomicAdd(&cur[d], 1);
        csr_src[p] = (int)(pr >> 32);
    }
}

// ---------------- W prep: Wt[l][n][k] = bf16(W_l[k][n]) ----------------

__global__ void k_prep_w(const float* __restrict__ Wa, const float* __restrict__ Wb,
                         const float* __restrict__ Wc, ushort* __restrict__ Wt) {
    int idx = blockIdx.x * 256 + threadIdx.x;  // 3*16384
    int layer = idx >> 14;
    int r = idx & 16383;
    int nn = r >> 7, kk = r & 127;
    const float* W = (layer == 0) ? Wa : (layer == 1) ? Wb : Wc;
    Wt[idx] = f2bf(W[kk * 128 + nn]);
}

// ---------------- MFMA GEMM (layer 1 only): xs = dinv .* (X_f32 @ W) ----------------

__launch_bounds__(256)
__global__ void k_gemm(const float* __restrict__ X, const ushort* __restrict__ Wt,
                       const float* __restrict__ dinv, ushort* __restrict__ C, int N) {
    __shared__ ushort As[128][136];
    __shared__ ushort Ws[128][136];
    const int t = threadIdx.x;
    const int row0 = blockIdx.x * 128;

#pragma unroll
    for (int i = 0; i < 8; i++) {
        int c = t + i * 256;
        int r = c >> 4, c8 = (c & 15) * 8;
        *(bf16x8*)&Ws[r][c8] = *(const bf16x8*)&Wt[r * 128 + c8];
    }
#pragma unroll
    for (int i = 0; i < 8; i++) {
        int c = t + i * 256;
        int r = c >> 4, c8 = (c & 15) * 8;
        int row = row0 + r;
        bf16x8 pk = {0, 0, 0, 0, 0, 0, 0, 0};
        if (row < N) {
            const float* sp = X + (size_t)row * FDIM + c8;
            float4 u0 = *(const float4*)(sp);
            float4 u1 = *(const float4*)(sp + 4);
            pk[0] = (short)f2bf(u0.x); pk[1] = (short)f2bf(u0.y);
            pk[2] = (short)f2bf(u0.z); pk[3] = (short)f2bf(u0.w);
            pk[4] = (short)f2bf(u1.x); pk[5] = (short)f2bf(u1.y);
            pk[6] = (short)f2bf(u1.z); pk[7] = (short)f2bf(u1.w);
        }
        *(bf16x8*)&As[r][c8] = pk;
    }
    __syncthreads();

    const int w = t >> 6, l = t & 63;
    const int m = l & 15, q = l >> 4;
    const int r0 = w * 32;

    bf16x8 a0[4], a1[4];
#pragma unroll
    for (int ks = 0; ks < 4; ks++) {
        a0[ks] = *(const bf16x8*)&As[r0 + m][ks * 32 + q * 8];
        a1[ks] = *(const bf16x8*)&As[r0 + 16 + m][ks * 32 + q * 8];
    }

    f32x4 acc0[8], acc1[8];
#pragma unroll
    for (int ct = 0; ct < 8; ct++) { acc0[ct] = {0, 0, 0, 0}; acc1[ct] = {0, 0, 0, 0}; }

#pragma unroll
    for (int ct = 0; ct < 8; ct++) {
#pragma unroll
        for (int ks = 0; ks < 4; ks++) {
            bf16x8 b = *(const bf16x8*)&Ws[ct * 16 + m][ks * 32 + q * 8];
            acc0[ct] = __builtin_amdgcn_mfma_f32_16x16x32_bf16(a0[ks], b, acc0[ct], 0, 0, 0);
            acc1[ct] = __builtin_amdgcn_mfma_f32_16x16x32_bf16(a1[ks], b, acc1[ct], 0, 0, 0);
        }
    }

    float dv0[4], dv1[4];
#pragma unroll
    for (int r = 0; r < 4; r++) {
        int row = row0 + r0 + q * 4 + r;
        dv0[r] = (row < N) ? dinv[row] : 0.f;
        dv1[r] = (row + 16 < N) ? dinv[row + 16] : 0.f;
    }
#pragma unroll
    for (int ct = 0; ct < 8; ct++) {
#pragma unroll
        for (int r = 0; r < 4; r++) {
            int row = row0 + r0 + q * 4 + r;
            if (row < N) C[(size_t)row * FDIM + ct * 16 + m] = f2bf(acc0[ct][r] * dv0[r]);
            int row2 = row + 16;
            if (row2 < N) C[(size_t)row2 * FDIM + ct * 16 + m] = f2bf(acc1[ct][r] * dv1[r]);
        }
    }
}

// ---------------- shared agg-into-LDS helper ----------------
// One wave64 per node: 4 row-groups x 16 lanes, 1 KB gather loads.
// Writes relu'd / biased bf16 row into As[r].

template<bool RELU>
static __device__ __forceinline__ void agg_rows_to_lds(
        const ushort* __restrict__ xs, const int* __restrict__ row_ptr,
        const int* __restrict__ csr_src, const float* __restrict__ dinv,
        const float* __restrict__ bias, ushort (*As)[136],
        int row0, int N, int t) {
    const int w = t >> 6, l = t & 63;
    const int fl = l & 15, grp = l >> 4;
    const u16x8* xsr = (const u16x8*)xs;

    for (int i = 0; i < 32; i++) {
        const int r = w * 32 + i;
        const int n = row0 + r;
        if (n >= N) {
            if (grp == 0) { u16x8 z = {0,0,0,0,0,0,0,0}; *(u16x8*)&As[r][fl * 8] = z; }
            continue;
        }
        float acc[8];
        u16x8 sv = xsr[(size_t)n * 16 + fl];
        const float selfw = (grp == 0) ? 1.f : 0.f;
#pragma unroll
        for (int k = 0; k < 8; k++) acc[k] = selfw * bf2f(sv[k]);

        const int beg = row_ptr[n];
        const int deg = row_ptr[n + 1] - beg;

        for (int base = 0; base < deg; base += 64) {
            const int m = min(64, deg - base);
            int idx = 0;
            if (l < m) idx = csr_src[beg + base + l];  // coalesced
            const int jmax = m & ~3;
#pragma unroll 2
            for (int j = 0; j < jmax; j += 4) {
                int s = __shfl(idx, j + grp, 64);
                u16x8 v = xsr[(size_t)s * 16 + fl];
#pragma unroll
                for (int k = 0; k < 8; k++) acc[k] += bf2f(v[k]);
            }
            const int rr = m - jmax;
            if (rr) {
                int s = __shfl(idx, jmax + (grp < rr ? grp : 0), 64);
                if (grp < rr) {
                    u16x8 v = xsr[(size_t)s * 16 + fl];
#pragma unroll
                    for (int k = 0; k < 8; k++) acc[k] += bf2f(v[k]);
                }
            }
        }

#pragma unroll
        for (int k = 0; k < 8; k++) {
            acc[k] += __shfl_xor(acc[k], 16, 64);
            acc[k] += __shfl_xor(acc[k], 32, 64);
        }

        if (grp == 0) {
            const float d = dinv[n];
            const float4 b0 = ((const float4*)bias)[fl * 2];
            const float4 b1 = ((const float4*)bias)[fl * 2 + 1];
            const float bb[8] = {b0.x, b0.y, b0.z, b0.w, b1.x, b1.y, b1.z, b1.w};
            u16x8 o;
#pragma unroll
            for (int k = 0; k < 8; k++) {
                float v = d * acc[k] + bb[k];
                if (RELU) v = fmaxf(v, 0.f);
                o[k] = f2bf(v);
            }
            *(u16x8*)&As[r][fl * 8] = o;
        }
    }
}

// ---------------- fused aggregate(layer k) + GEMM(layer k+1) ----------------
// out = dinv .* (relu(agg) @ W); B-fragments straight from L1-resident Wt.

__launch_bounds__(256)
__global__ void k_agg_gemm(const ushort* __restrict__ xs, const int* __restrict__ row_ptr,
                           const int* __restrict__ csr_src, const float* __restrict__ dinv,
                           const float* __restrict__ bias, const ushort* __restrict__ Wt,
                           ushort* __restrict__ C, int N) {
    __shared__ ushort As[128][136];
    const int t = threadIdx.x;
    const int row0 = blockIdx.x * 128;

    agg_rows_to_lds<true>(xs, row_ptr, csr_src, dinv, bias, As, row0, N, t);
    __syncthreads();

    const int w = t >> 6, l = t & 63;
    const int m = l & 15, q = l >> 4;
    const int r0 = w * 32;

    bf16x8 a0[4], a1[4];
#pragma unroll
    for (int ks = 0; ks < 4; ks++) {
        a0[ks] = *(const bf16x8*)&As[r0 + m][ks * 32 + q * 8];
        a1[ks] = *(const bf16x8*)&As[r0 + 16 + m][ks * 32 + q * 8];
    }

    f32x4 acc0[8], acc1[8];
#pragma unroll
    for (int ct = 0; ct < 8; ct++) { acc0[ct] = {0, 0, 0, 0}; acc1[ct] = {0, 0, 0, 0}; }

#pragma unroll
    for (int ct = 0; ct < 8; ct++) {
#pragma unroll
        for (int ks = 0; ks < 4; ks++) {
            bf16x8 b = *(const bf16x8*)&Wt[(ct * 16 + m) * 128 + ks * 32 + q * 8];
            acc0[ct] = __builtin_amdgcn_mfma_f32_16x16x32_bf16(a0[ks], b, acc0[ct], 0, 0, 0);
            acc1[ct] = __builtin_amdgcn_mfma_f32_16x16x32_bf16(a1[ks], b, acc1[ct], 0, 0, 0);
        }
    }

    float dv0[4], dv1[4];
#pragma unroll
    for (int r = 0; r < 4; r++) {
        int row = row0 + r0 + q * 4 + r;
        dv0[r] = (row < N) ? dinv[row] : 0.f;
        dv1[r] = (row + 16 < N) ? dinv[row + 16] : 0.f;
    }
#pragma unroll
    for (int ct = 0; ct < 8; ct++) {
#pragma unroll
        for (int r = 0; r < 4; r++) {
            int row = row0 + r0 + q * 4 + r;
            if (row < N) C[(size_t)row * FDIM + ct * 16 + m] = f2bf(acc0[ct][r] * dv0[r]);
            int row2 = row + 16;
            if (row2 < N) C[(size_t)row2 * FDIM + ct * 16 + m] = f2bf(acc1[ct][r] * dv1[r]);
        }
    }
}

// ---------------- fused aggregate(layer 3, no relu) + batch mean-pool ----------------

__launch_bounds__(256)
__global__ void k_agg_pool(const ushort* __restrict__ xs, const int* __restrict__ row_ptr,
                           const int* __restrict__ csr_src, const float* __restrict__ dinv,
                           const float* __restrict__ bias, const int* __restrict__ batch,
                           float* __restrict__ gsums, int N) {
    __shared__ ushort As[128][136];
    const int t = threadIdx.x;
    const int row0 = blockIdx.x * 128;

    agg_rows_to_lds<false>(xs, row_ptr, csr_src, dinv, bias, As, row0, N, t);
    __syncthreads();

    if (t < FDIM) {
        const int lim = min(128, N - row0);
        float acc = 0.f;
        int cur = batch[row0];
        for (int i = 0; i < lim; i++) {
            int g = batch[row0 + i];
            if (g != cur) {
                atomicAdd(&gsums[cur * FDIM + t], acc);
                acc = 0.f;
                cur = g;
            }
            acc += bf2f(As[i][t]);
        }
        atomicAdd(&gsums[cur * FDIM + t], acc);
    }
}

// ---------------- per-graph mean + MLP + LayerNorm ----------------

__launch_bounds__(128)
__global__ void k_final(const float* __restrict__ sums, const int* __restrict__ batch, int N,
                        const float* __restrict__ Wm1, const float* __restrict__ bm1,
                        const float* __restrict__ Wm2, const float* __restrict__ bm2,
                        const float* __restrict__ ln_g, const float* __restrict__ ln_b,
                        float* __restrict__ out) {
    const int g = blockIdx.x;
    const int t = threadIdx.x;

    int lo = 0, hi = N;
    while (lo < hi) { int mid = (lo + hi) >> 1; if (batch[mid] < g) lo = mid + 1; else hi = mid; }
    int lo2 = lo, hi2 = N;
    while (lo2 < hi2) { int mid = (lo2 + hi2) >> 1; if (batch[mid] < g + 1) lo2 = mid + 1; else hi2 = mid; }
    float cnt = (float)(lo2 - lo);

    float gl = sums[g * FDIM + t] / fmaxf(cnt, 1.0f);

    __shared__ float gbuf[FDIM];
    __shared__ float hbuf[FDIM];
    __shared__ float wsum[4];
    gbuf[t] = gl;
    __syncthreads();

    float h = bm1[t];
#pragma unroll 8
    for (int k = 0; k < FDIM; k++) h += gbuf[k] * Wm1[k * FDIM + t];
    h = fmaxf(h, 0.f);
    hbuf[t] = h;
    __syncthreads();

    float y = bm2[t];
#pragma unroll 8
    for (int k = 0; k < FDIM; k++) y += hbuf[k] * Wm2[k * FDIM + t];

    float s = y, s2 = y * y;
#pragma unroll
    for (int off = 32; off > 0; off >>= 1) {
        s += __shfl_down(s, off, 64);
        s2 += __shfl_down(s2, off, 64);
    }
    if ((t & 63) == 0) { wsum[t >> 6] = s; wsum[2 + (t >> 6)] = s2; }
    __syncthreads();
    float sum = wsum[0] + wsum[1];
    float sumsq = wsum[2] + wsum[3];
    float mu = sum * (1.0f / FDIM);
    float var = sumsq * (1.0f / FDIM) - mu * mu;
    float r = rsqrtf(var + LN_EPS);
    out[g * FDIM + t] = (y - mu) * r * ln_g[t] + ln_b[t];
}

// ---------------- launch ----------------

extern "C" void kernel_launch(void* const* d_in, const int* in_sizes, int n_in,
                              void* d_out, int out_size, void* d_ws, size_t ws_size,
                              hipStream_t stream) {
    const float* x_in  = (const float*)d_in[0];
    const int*   eidx  = (const int*)d_in[1];
    const int*   batch = (const int*)d_in[2];
    const float* W1 = (const float*)d_in[3];
    const float* b1 = (const float*)d_in[4];
    const float* W2 = (const float*)d_in[5];
    const float* b2 = (const float*)d_in[6];
    const float* W3 = (const float*)d_in[7];
    const float* b3 = (const float*)d_in[8];
    const float* Wm1 = (const float*)d_in[9];
    const float* bm1 = (const float*)d_in[10];
    const float* Wm2 = (const float*)d_in[11];
    const float* bm2 = (const float*)d_in[12];
    const float* ln_g = (const float*)d_in[13];
    const float* ln_b = (const float*)d_in[14];
    float* out = (float*)d_out;

    const int N = in_sizes[0] / FDIM;   // 100000
    const int E = in_sizes[1] / 2;      // 1600000
    const int G = out_size / FDIM;      // 64

    const int* src = eidx;
    const int* dst = eidx + E;

    // workspace layout
    char* p = (char*)d_ws;
    u64* bktA = (u64*)p;              p += (size_t)E * 8;
    ushort* B0h = (ushort*)p;         p += (size_t)N * FDIM * 2;
    ushort* B1h = (ushort*)p;         p += (size_t)N * FDIM * 2;
    int* csr_src = (int*)p;           p += (size_t)E * 4;
    int* row_ptr = (int*)p;           p += (size_t)(N + 4) * 4;
    float* dinv = (float*)p;          p += (size_t)N * 4;
    float* gsums = (float*)p;         p += (size_t)G * FDIM * 4;
    ushort* Wt = (ushort*)p;          p += 3 * 16384 * 2;
    int* ghist = (int*)p;             p += MAXBKT * 4;
    int* bbase = (int*)p;             p += (MAXBKT + 4) * 4;
    int* bcur = (int*)p;              p += MAXBKT * 4;

    const int TPB = 256;
    dim3 blk(TPB);
    dim3 gTile((N + 127) / 128);
    const int nbkt = (N + BKT_NODES - 1) >> NBKT_SHIFT;
    const int nEb = (E + 2047) / 2048;

    // ---- bucketed CSR build ----
    hipMemsetAsync(ghist, 0, MAXBKT * 4, stream);
    hipMemsetAsync(gsums, 0, (size_t)G * FDIM * 4, stream);
    k_bkt_hist<<<dim3(nEb), blk, 0, stream>>>(dst, ghist, E, nbkt);
    k_bkt_scan<<<dim3(1), dim3(64), 0, stream>>>(ghist, bbase, bcur, nbkt);
    k_bkt_scatter<<<dim3(nEb), blk, 0, stream>>>(src, dst, bcur, bktA, E, nbkt);
    k_build<<<dim3(nbkt), dim3(1024), 0, stream>>>(bktA, bbase, row_ptr, dinv, csr_src, N);
    k_prep_w<<<dim3(192), blk, 0, stream>>>(W1, W2, W3, Wt);

    // ---- layer 1 GEMM (fp32 input) ----
    k_gemm<<<gTile, blk, 0, stream>>>(x_in, Wt, dinv, B0h, N);

    // ---- agg1 + GEMM2 ----
    k_agg_gemm<<<gTile, blk, 0, stream>>>(B0h, row_ptr, csr_src, dinv, b1,
                                          Wt + 16384, B1h, N);
    // ---- agg2 + GEMM3 ----
    k_agg_gemm<<<gTile, blk, 0, stream>>>(B1h, row_ptr, csr_src, dinv, b2,
                                          Wt + 32768, B0h, N);
    // ---- agg3 + pool ----
    k_agg_pool<<<gTile, blk, 0, stream>>>(B0h, row_ptr, csr_src, dinv, b3,
                                          batch, gsums, N);

    // ---- MLP + LN ----
    k_final<<<dim3(G), dim3(FDIM), 0, stream>>>(gsums, batch, N, Wm1, bm1, Wm2, bm2,
                                                ln_g, ln_b, out);
}

// Round 9
// 488.552 us; speedup vs baseline: 1.6140x; 1.6140x over previous
//
#include <hip/hip_runtime.h>

#define FDIM 128
#define LN_EPS 1e-5f
#define NBKT_SHIFT 10          // 1024 nodes per bucket
#define BKT_NODES 1024
#define MAXBKT 128             // supports N <= 131072
#define CAP_SHIFT 15           // 32768 edge capacity per bucket (mean 16384, ~8 sigma)
#define BKT_CAP 32768

typedef short bf16x8 __attribute__((ext_vector_type(8)));
typedef float f32x4 __attribute__((ext_vector_type(4)));
typedef ushort u16x8 __attribute__((ext_vector_type(8)));
typedef unsigned long long u64;

static __device__ __forceinline__ ushort f2bf(float f) {
    union { float f; unsigned u; } v; v.f = f;
    unsigned r = v.u + 0x7FFFu + ((v.u >> 16) & 1u);  // RNE
    return (ushort)(r >> 16);
}
static __device__ __forceinline__ float bf2f(ushort h) {
    union { unsigned u; float f; } v; v.u = ((unsigned)h) << 16;
    return v.f;
}

// ---------------- bucketed edge scatter (fixed-capacity buckets) ----------------
// Each block reserves one contiguous run per bucket via bcur; bucket b lives at
// bktA[b*BKT_CAP ...]. No histogram pre-pass needed.

__launch_bounds__(256)
__global__ void k_bkt_scatter(const int* __restrict__ src, const int* __restrict__ dst,
                              int* __restrict__ bcur, u64* __restrict__ bktA,
                              int E, int nbkt) {
    __shared__ int h[MAXBKT], lbase[MAXBKT], lcur[MAXBKT];
    const int t = threadIdx.x;
    for (int i = t; i < nbkt; i += 256) h[i] = 0;
    __syncthreads();
    const int E4 = E >> 2;   // E assumed multiple of 4 (1.6M is)
    const int4* s4p = (const int4*)src;
    const int4* d4p = (const int4*)dst;
    int4 sv[2], dv[2]; bool ok[2];
#pragma unroll
    for (int r = 0; r < 2; r++) {
        int i4 = blockIdx.x * 512 + r * 256 + t;
        ok[r] = (i4 < E4);
        if (ok[r]) {
            sv[r] = s4p[i4]; dv[r] = d4p[i4];
            atomicAdd(&h[dv[r].x >> NBKT_SHIFT], 1);
            atomicAdd(&h[dv[r].y >> NBKT_SHIFT], 1);
            atomicAdd(&h[dv[r].z >> NBKT_SHIFT], 1);
            atomicAdd(&h[dv[r].w >> NBKT_SHIFT], 1);
        }
    }
    __syncthreads();
    for (int i = t; i < nbkt; i += 256) {
        lbase[i] = h[i] ? ((i << CAP_SHIFT) + atomicAdd(&bcur[i], h[i])) : 0;
        lcur[i] = 0;
    }
    __syncthreads();
#pragma unroll
    for (int r = 0; r < 2; r++) {
        if (!ok[r]) continue;
        int ss[4] = {sv[r].x, sv[r].y, sv[r].z, sv[r].w};
        int dd[4] = {dv[r].x, dv[r].y, dv[r].z, dv[r].w};
#pragma unroll
        for (int j = 0; j < 4; j++) {
            int b = dd[j] >> NBKT_SHIFT;
            int p = atomicAdd(&lcur[b], 1);
            bktA[(size_t)lbase[b] + p] = ((u64)(unsigned)ss[j] << 32) | (unsigned)dd[j];
        }
    }
}

// merged per-bucket: degree count -> LDS scan -> rowinfo/dinv -> CSR fill
// CSR is bucket-padded: node rows of bucket b live in csr_src[b*BKT_CAP ...].

__launch_bounds__(1024)
__global__ void k_build(const u64* __restrict__ bktA, const int* __restrict__ bcur,
                        int2* __restrict__ rowinfo, float* __restrict__ dinv,
                        int* __restrict__ csr_src, int N) {
    __shared__ int cnt[BKT_NODES];
    __shared__ int scan[BKT_NODES];
    __shared__ int cur[BKT_NODES];
    const int t = threadIdx.x;
    const int b = blockIdx.x;
    const int nb = b << NBKT_SHIFT;
    cnt[t] = 0;
    __syncthreads();
    const int beg = b << CAP_SHIFT;
    const int end = beg + bcur[b];
    for (int i = beg + t; i < end; i += 1024)
        atomicAdd(&cnt[(int)(unsigned)bktA[i] - nb], 1);
    __syncthreads();
    int my = cnt[t];
    scan[t] = my;
    __syncthreads();
#pragma unroll
    for (int off = 1; off < 1024; off <<= 1) {
        int v = (t >= off) ? scan[t - off] : 0;
        __syncthreads();
        scan[t] += v;
        __syncthreads();
    }
    const int rbeg = beg + scan[t] - my;   // exclusive start within padded CSR
    cur[t] = rbeg;
    const int n = nb + t;
    if (n < N) {
        rowinfo[n] = make_int2(rbeg, my);
        dinv[n] = rsqrtf((float)(my + 1));  // +1 self-loop
    }
    __syncthreads();
    for (int i = beg + t; i < end; i += 1024) {
        u64 pr = bktA[i];
        int d = (int)(unsigned)pr - nb;
        int p = atomicAdd(&cur[d], 1);
        csr_src[p] = (int)(pr >> 32);
    }
}

// ---------------- W prep: Wt[l][n][k] = bf16(W_l[k][n]) ----------------

__global__ void k_prep_w(const float* __restrict__ Wa, const float* __restrict__ Wb,
                         const float* __restrict__ Wc, ushort* __restrict__ Wt) {
    int idx = blockIdx.x * 256 + threadIdx.x;  // 3*16384
    int layer = idx >> 14;
    int r = idx & 16383;
    int nn = r >> 7, kk = r & 127;
    const float* W = (layer == 0) ? Wa : (layer == 1) ? Wb : Wc;
    Wt[idx] = f2bf(W[kk * 128 + nn]);
}

// ---------------- MFMA GEMM: xs[N,128](bf16) = dinv .* (X[N,128] @ W) ----------------

template<bool F32IN>
__launch_bounds__(256)
__global__ void k_gemm(const void* __restrict__ Xv, const ushort* __restrict__ Wt,
                       const float* __restrict__ dinv, ushort* __restrict__ C, int N) {
    __shared__ ushort As[128][136];
    __shared__ ushort Ws[128][136];
    const int t = threadIdx.x;
    const int row0 = blockIdx.x * 128;

#pragma unroll
    for (int i = 0; i < 8; i++) {
        int c = t + i * 256;
        int r = c >> 4, c8 = (c & 15) * 8;
        *(bf16x8*)&Ws[r][c8] = *(const bf16x8*)&Wt[r * 128 + c8];
    }
    if (F32IN) {
        const float* X = (const float*)Xv;
#pragma unroll
        for (int i = 0; i < 8; i++) {
            int c = t + i * 256;
            int r = c >> 4, c8 = (c & 15) * 8;
            int row = row0 + r;
            bf16x8 pk = {0, 0, 0, 0, 0, 0, 0, 0};
            if (row < N) {
                const float* sp = X + (size_t)row * FDIM + c8;
                float4 u0 = *(const float4*)(sp);
                float4 u1 = *(const float4*)(sp + 4);
                pk[0] = (short)f2bf(u0.x); pk[1] = (short)f2bf(u0.y);
                pk[2] = (short)f2bf(u0.z); pk[3] = (short)f2bf(u0.w);
                pk[4] = (short)f2bf(u1.x); pk[5] = (short)f2bf(u1.y);
                pk[6] = (short)f2bf(u1.z); pk[7] = (short)f2bf(u1.w);
            }
            *(bf16x8*)&As[r][c8] = pk;
        }
    } else {
        const ushort* X = (const ushort*)Xv;
#pragma unroll
        for (int i = 0; i < 8; i++) {
            int c = t + i * 256;
            int r = c >> 4, c8 = (c & 15) * 8;
            int row = row0 + r;
            bf16x8 pk = {0, 0, 0, 0, 0, 0, 0, 0};
            if (row < N) pk = *(const bf16x8*)&X[(size_t)row * FDIM + c8];
            *(bf16x8*)&As[r][c8] = pk;
        }
    }
    __syncthreads();

    const int w = t >> 6, l = t & 63;
    const int m = l & 15, q = l >> 4;
    const int r0 = w * 32;

    bf16x8 a0[4], a1[4];
#pragma unroll
    for (int ks = 0; ks < 4; ks++) {
        a0[ks] = *(const bf16x8*)&As[r0 + m][ks * 32 + q * 8];
        a1[ks] = *(const bf16x8*)&As[r0 + 16 + m][ks * 32 + q * 8];
    }

    f32x4 acc0[8], acc1[8];
#pragma unroll
    for (int ct = 0; ct < 8; ct++) { acc0[ct] = {0, 0, 0, 0}; acc1[ct] = {0, 0, 0, 0}; }

#pragma unroll
    for (int ct = 0; ct < 8; ct++) {
#pragma unroll
        for (int ks = 0; ks < 4; ks++) {
            bf16x8 b = *(const bf16x8*)&Ws[ct * 16 + m][ks * 32 + q * 8];
            acc0[ct] = __builtin_amdgcn_mfma_f32_16x16x32_bf16(a0[ks], b, acc0[ct], 0, 0, 0);
            acc1[ct] = __builtin_amdgcn_mfma_f32_16x16x32_bf16(a1[ks], b, acc1[ct], 0, 0, 0);
        }
    }

    float dv0[4], dv1[4];
#pragma unroll
    for (int r = 0; r < 4; r++) {
        int row = row0 + r0 + q * 4 + r;
        dv0[r] = (row < N) ? dinv[row] : 0.f;
        dv1[r] = (row + 16 < N) ? dinv[row + 16] : 0.f;
    }
#pragma unroll
    for (int ct = 0; ct < 8; ct++) {
#pragma unroll
        for (int r = 0; r < 4; r++) {
            int row = row0 + r0 + q * 4 + r;
            if (row < N) C[(size_t)row * FDIM + ct * 16 + m] = f2bf(acc0[ct][r] * dv0[r]);
            int row2 = row + 16;
            if (row2 < N) C[(size_t)row2 * FDIM + ct * 16 + m] = f2bf(acc1[ct][r] * dv1[r]);
        }
    }
}

// ---------------- fused pull-aggregate, one node per wave64 ----------------
// 4 row-groups of 16 lanes; one load instruction fetches 4 src rows (1 KB).
// Explicit 1-deep prefetch: gather j+4 issued before consuming j.
// out[n] = act(dinv[n]*(xs[n] + sum_e xs[csr_src[e]]) + b)

__launch_bounds__(256)
__global__ void k_aggregate(const ushort* __restrict__ xs, const int2* __restrict__ rowinfo,
                            const int* __restrict__ csr_src, const float* __restrict__ dinv,
                            const float* __restrict__ bias, ushort* __restrict__ out,
                            int N, int do_relu) {
    const int n = (blockIdx.x << 2) + (threadIdx.x >> 6);
    if (n >= N) return;
    const int l = threadIdx.x & 63;
    const int fl = l & 15;      // feature slot: features fl*8 .. fl*8+7
    const int grp = l >> 4;     // row group 0..3

    const u16x8* xsr = (const u16x8*)xs;

    float acc[8];
    u16x8 sv = xsr[(size_t)n * 16 + fl];
    const float selfw = (grp == 0) ? 1.f : 0.f;
#pragma unroll
    for (int k = 0; k < 8; k++) acc[k] = selfw * bf2f(sv[k]);

    const int2 ri = rowinfo[n];
    const int beg = ri.x;
    const int deg = ri.y;

    for (int base = 0; base < deg; base += 64) {
        const int m = min(64, deg - base);
        int idx = 0;
        if (l < m) idx = csr_src[beg + base + l];  // coalesced
        int j = grp;
        if (j < m) {
            int s = __shfl(idx, j, 64);
            u16x8 v = xsr[(size_t)s * 16 + fl];
#pragma unroll 2
            for (j += 4; j < m; j += 4) {
                int s2 = __shfl(idx, j, 64);
                u16x8 v2 = xsr[(size_t)s2 * 16 + fl];   // prefetch next
#pragma unroll
                for (int k = 0; k < 8; k++) acc[k] += bf2f(v[k]);
                v = v2;
            }
#pragma unroll
            for (int k = 0; k < 8; k++) acc[k] += bf2f(v[k]);
        }
    }

    // reduce the 4 row-groups
#pragma unroll
    for (int k = 0; k < 8; k++) {
        acc[k] += __shfl_xor(acc[k], 16, 64);
        acc[k] += __shfl_xor(acc[k], 32, 64);
    }

    if (grp == 0) {
        const float d = dinv[n];
        const float4 b0 = ((const float4*)bias)[fl * 2];
        const float4 b1 = ((const float4*)bias)[fl * 2 + 1];
        const float bb[8] = {b0.x, b0.y, b0.z, b0.w, b1.x, b1.y, b1.z, b1.w};
        u16x8 o;
#pragma unroll
        for (int k = 0; k < 8; k++) {
            float v = d * acc[k] + bb[k];
            if (do_relu) v = fmaxf(v, 0.f);
            o[k] = f2bf(v);
        }
        ((u16x8*)out)[(size_t)n * 16 + fl] = o;
    }
}

// ---------------- two-stage pool ----------------

#define POOL_NODES 128

__launch_bounds__(128)
__global__ void k_pool(const ushort* __restrict__ x3, const int* __restrict__ batch,
                       float* __restrict__ sums, int N) {
    const int t = threadIdx.x;
    const int n0 = blockIdx.x * POOL_NODES;
    if (n0 >= N) return;
    const int n1 = (n0 + POOL_NODES < N) ? n0 + POOL_NODES : N;

    float acc = 0.f;
    int cur = batch[n0];
    for (int n = n0; n < n1; n++) {
        int g = batch[n];
        if (g != cur) {
            atomicAdd(&sums[cur * FDIM + t], acc);
            acc = 0.f;
            cur = g;
        }
        acc += bf2f(x3[(size_t)n * FDIM + t]);
    }
    atomicAdd(&sums[cur * FDIM + t], acc);
}

// ---------------- per-graph mean + MLP + LayerNorm ----------------

__launch_bounds__(128)
__global__ void k_final(const float* __restrict__ sums, const int* __restrict__ batch, int N,
                        const float* __restrict__ Wm1, const float* __restrict__ bm1,
                        const float* __restrict__ Wm2, const float* __restrict__ bm2,
                        const float* __restrict__ ln_g, const float* __restrict__ ln_b,
                        float* __restrict__ out) {
    const int g = blockIdx.x;
    const int t = threadIdx.x;

    int lo = 0, hi = N;
    while (lo < hi) { int mid = (lo + hi) >> 1; if (batch[mid] < g) lo = mid + 1; else hi = mid; }
    int lo2 = lo, hi2 = N;
    while (lo2 < hi2) { int mid = (lo2 + hi2) >> 1; if (batch[mid] < g + 1) lo2 = mid + 1; else hi2 = mid; }
    float cnt = (float)(lo2 - lo);

    float gl = sums[g * FDIM + t] / fmaxf(cnt, 1.0f);

    __shared__ float gbuf[FDIM];
    __shared__ float hbuf[FDIM];
    __shared__ float wsum[4];
    gbuf[t] = gl;
    __syncthreads();

    float h = bm1[t];
#pragma unroll 8
    for (int k = 0; k < FDIM; k++) h += gbuf[k] * Wm1[k * FDIM + t];
    h = fmaxf(h, 0.f);
    hbuf[t] = h;
    __syncthreads();

    float y = bm2[t];
#pragma unroll 8
    for (int k = 0; k < FDIM; k++) y += hbuf[k] * Wm2[k * FDIM + t];

    float s = y, s2 = y * y;
#pragma unroll
    for (int off = 32; off > 0; off >>= 1) {
        s += __shfl_down(s, off, 64);
        s2 += __shfl_down(s2, off, 64);
    }
    if ((t & 63) == 0) { wsum[t >> 6] = s; wsum[2 + (t >> 6)] = s2; }
    __syncthreads();
    float sum = wsum[0] + wsum[1];
    float sumsq = wsum[2] + wsum[3];
    float mu = sum * (1.0f / FDIM);
    float var = sumsq * (1.0f / FDIM) - mu * mu;
    float r = rsqrtf(var + LN_EPS);
    out[g * FDIM + t] = (y - mu) * r * ln_g[t] + ln_b[t];
}

// ---------------- launch ----------------

extern "C" void kernel_launch(void* const* d_in, const int* in_sizes, int n_in,
                              void* d_out, int out_size, void* d_ws, size_t ws_size,
                              hipStream_t stream) {
    const float* x_in  = (const float*)d_in[0];
    const int*   eidx  = (const int*)d_in[1];
    const int*   batch = (const int*)d_in[2];
    const float* W1 = (const float*)d_in[3];
    const float* b1 = (const float*)d_in[4];
    const float* W2 = (const float*)d_in[5];
    const float* b2 = (const float*)d_in[6];
    const float* W3 = (const float*)d_in[7];
    const float* b3 = (const float*)d_in[8];
    const float* Wm1 = (const float*)d_in[9];
    const float* bm1 = (const float*)d_in[10];
    const float* Wm2 = (const float*)d_in[11];
    const float* bm2 = (const float*)d_in[12];
    const float* ln_g = (const float*)d_in[13];
    const float* ln_b = (const float*)d_in[14];
    float* out = (float*)d_out;

    const int N = in_sizes[0] / FDIM;   // 100000
    const int E = in_sizes[1] / 2;      // 1600000
    const int G = out_size / FDIM;      // 64

    const int* src = eidx;
    const int* dst = eidx + E;

    const int nbkt = (N + BKT_NODES - 1) >> NBKT_SHIFT;        // 98

    // workspace layout
    char* p = (char*)d_ws;
    u64* bktA = (u64*)p;              p += (size_t)nbkt * BKT_CAP * 8;   // 25.7 MB
    ushort* B0h = (ushort*)p;         p += (size_t)N * FDIM * 2;         // 25.6 MB
    ushort* B1h = (ushort*)p;         p += (size_t)N * FDIM * 2;         // 25.6 MB
    int* csr_src = (int*)p;           p += (size_t)nbkt * BKT_CAP * 4;   // 12.8 MB
    int2* rowinfo = (int2*)p;         p += (size_t)N * 8;
    float* dinv = (float*)p;          p += (size_t)N * 4;
    ushort* Wt = (ushort*)p;          p += 3 * 16384 * 2;
    float* gsums = (float*)p;         p += (size_t)G * FDIM * 4;         // zeroed
    int* bcur = (int*)p;              p += MAXBKT * 4;                   // zeroed

    const int TPB = 256;
    dim3 blk(TPB);
    dim3 gAgg((N + 3) / 4);
    dim3 gTile((N + 127) / 128);
    const int nEb = (E + 2047) / 2048;

    // ---- build (gsums and bcur are adjacent -> one memset) ----
    hipMemsetAsync(gsums, 0, (size_t)G * FDIM * 4 + MAXBKT * 4, stream);
    k_bkt_scatter<<<dim3(nEb), blk, 0, stream>>>(src, dst, bcur, bktA, E, nbkt);
    k_build<<<dim3(nbkt), dim3(1024), 0, stream>>>(bktA, bcur, rowinfo, dinv, csr_src, N);
    k_prep_w<<<dim3(192), blk, 0, stream>>>(W1, W2, W3, Wt);

    // ---- layer 1 (fp32 input) ----
    k_gemm<true><<<gTile, blk, 0, stream>>>(x_in, Wt, dinv, B0h, N);
    k_aggregate<<<gAgg, blk, 0, stream>>>(B0h, rowinfo, csr_src, dinv, b1, B1h, N, 1);

    // ---- layer 2 ----
    k_gemm<false><<<gTile, blk, 0, stream>>>(B1h, Wt + 16384, dinv, B0h, N);
    k_aggregate<<<gAgg, blk, 0, stream>>>(B0h, rowinfo, csr_src, dinv, b2, B1h, N, 1);

    // ---- layer 3 (no relu) ----
    k_gemm<false><<<gTile, blk, 0, stream>>>(B1h, Wt + 32768, dinv, B0h, N);
    k_aggregate<<<gAgg, blk, 0, stream>>>(B0h, rowinfo, csr_src, dinv, b3, B1h, N, 0);

    // ---- pool + MLP + LN ----
    k_pool<<<dim3((N + POOL_NODES - 1) / POOL_NODES), dim3(FDIM), 0, stream>>>(B1h, batch, gsums, N);
    k_final<<<dim3(G), dim3(FDIM), 0, stream>>>(gsums, batch, N, Wm1, bm1, Wm2, bm2,
                                                ln_g, ln_b, out);
}

// Round 10
// 480.564 us; speedup vs baseline: 1.6408x; 1.0166x over previous
//
#include <hip/hip_runtime.h>

#define FDIM 128
#define LN_EPS 1e-5f
#define NBKT_SHIFT 10          // 1024 nodes per bucket
#define BKT_NODES 1024
#define MAXBKT 128             // supports N <= 131072
#define CAP_SHIFT 15           // 32768 edge capacity per bucket (mean 16384, ~8 sigma)
#define BKT_CAP 32768

typedef short bf16x8 __attribute__((ext_vector_type(8)));
typedef float f32x4 __attribute__((ext_vector_type(4)));
typedef float f32x2 __attribute__((ext_vector_type(2)));
typedef ushort u16x8 __attribute__((ext_vector_type(8)));
typedef unsigned long long u64;

static __device__ __forceinline__ ushort f2bf(float f) {
    union { float f; unsigned u; } v; v.f = f;
    unsigned r = v.u + 0x7FFFu + ((v.u >> 16) & 1u);  // RNE
    return (ushort)(r >> 16);
}
static __device__ __forceinline__ float bf2f(ushort h) {
    union { unsigned u; float f; } v; v.u = ((unsigned)h) << 16;
    return v.f;
}
// fp8 e4m3 (OCP on gfx950) encode/decode via HW converts
static __device__ __forceinline__ unsigned char f2fp8(float f) {
    return (unsigned char)__builtin_amdgcn_cvt_pk_fp8_f32(f, f, 0u, false);
}
static __device__ __forceinline__ void fp8x8_add(uint2 w, float* acc) {
    f32x2 p0 = __builtin_amdgcn_cvt_pk_f32_fp8(w.x, false);
    f32x2 p1 = __builtin_amdgcn_cvt_pk_f32_fp8(w.x, true);
    f32x2 p2 = __builtin_amdgcn_cvt_pk_f32_fp8(w.y, false);
    f32x2 p3 = __builtin_amdgcn_cvt_pk_f32_fp8(w.y, true);
    acc[0] += p0[0]; acc[1] += p0[1]; acc[2] += p1[0]; acc[3] += p1[1];
    acc[4] += p2[0]; acc[5] += p2[1]; acc[6] += p3[0]; acc[7] += p3[1];
}

// ---------------- bucketed edge scatter (fixed-capacity buckets) ----------------
// 2-way replicated LDS histograms/cursors: two independent 128-thread halves,
// each reserves its own contiguous runs -> half the LDS-atomic serialization.

__launch_bounds__(256)
__global__ void k_bkt_scatter(const int* __restrict__ src, const int* __restrict__ dst,
                              int* __restrict__ bcur, u64* __restrict__ bktA,
                              int E, int nbkt) {
    __shared__ int h[2][MAXBKT], lbase[2][MAXBKT], lcur[2][MAXBKT];
    const int t = threadIdx.x;
    const int half = t >> 7;
    for (int i = t; i < 2 * MAXBKT; i += 256) ((int*)h)[i] = 0;
    __syncthreads();
    const int E4 = E >> 2;   // E multiple of 4
    const int4* s4p = (const int4*)src;
    const int4* d4p = (const int4*)dst;
    int4 sv[2], dv[2]; bool ok[2];
#pragma unroll
    for (int r = 0; r < 2; r++) {
        int i4 = blockIdx.x * 512 + r * 256 + t;
        ok[r] = (i4 < E4);
        if (ok[r]) {
            sv[r] = s4p[i4]; dv[r] = d4p[i4];
            atomicAdd(&h[half][dv[r].x >> NBKT_SHIFT], 1);
            atomicAdd(&h[half][dv[r].y >> NBKT_SHIFT], 1);
            atomicAdd(&h[half][dv[r].z >> NBKT_SHIFT], 1);
            atomicAdd(&h[half][dv[r].w >> NBKT_SHIFT], 1);
        }
    }
    __syncthreads();
    for (int i = t; i < 2 * nbkt; i += 256) {
        const int hh = (i >= nbkt) ? 1 : 0;
        const int b = hh ? (i - nbkt) : i;
        const int c = h[hh][b];
        lbase[hh][b] = c ? ((b << CAP_SHIFT) + atomicAdd(&bcur[b], c)) : 0;
        lcur[hh][b] = 0;
    }
    __syncthreads();
#pragma unroll
    for (int r = 0; r < 2; r++) {
        if (!ok[r]) continue;
        int ss[4] = {sv[r].x, sv[r].y, sv[r].z, sv[r].w};
        int dd[4] = {dv[r].x, dv[r].y, dv[r].z, dv[r].w};
#pragma unroll
        for (int j = 0; j < 4; j++) {
            int b = dd[j] >> NBKT_SHIFT;
            int p = atomicAdd(&lcur[half][b], 1);
            bktA[(size_t)lbase[half][b] + p] = ((u64)(unsigned)ss[j] << 32) | (unsigned)dd[j];
        }
    }
}

// merged per-bucket: degree count -> wave-level scan -> rowinfo/dinv -> CSR fill

__launch_bounds__(1024)
__global__ void k_build(const u64* __restrict__ bktA, const int* __restrict__ bcur,
                        int2* __restrict__ rowinfo, float* __restrict__ dinv,
                        int* __restrict__ csr_src, int N) {
    __shared__ int cnt[BKT_NODES];
    __shared__ int cur[BKT_NODES];
    __shared__ int wpart[16], wbase[16];
    const int t = threadIdx.x;
    const int b = blockIdx.x;
    const int nb = b << NBKT_SHIFT;
    cnt[t] = 0;
    __syncthreads();
    const int beg = b << CAP_SHIFT;
    const int end = beg + bcur[b];
    for (int i = beg + t; i < end; i += 1024)
        atomicAdd(&cnt[(int)(unsigned)bktA[i] - nb], 1);
    __syncthreads();
    const int lane = t & 63, wv = t >> 6;
    const int my = cnt[t];
    int x = my;
#pragma unroll
    for (int off = 1; off < 64; off <<= 1) {
        int y = __shfl_up(x, off, 64);
        if (lane >= off) x += y;
    }
    if (lane == 63) wpart[wv] = x;
    __syncthreads();
    if (t == 0) {
        int s = 0;
        for (int w = 0; w < 16; w++) { int tmp = wpart[w]; wbase[w] = s; s += tmp; }
    }
    __syncthreads();
    const int incl = x + wbase[wv];
    const int rbeg = beg + incl - my;   // exclusive start within padded CSR
    cur[t] = rbeg;
    const int n = nb + t;
    if (n < N) {
        rowinfo[n] = make_int2(rbeg, my);
        dinv[n] = rsqrtf((float)(my + 1));  // +1 self-loop
    }
    __syncthreads();
    for (int i = beg + t; i < end; i += 1024) {
        u64 pr = bktA[i];
        int d = (int)(unsigned)pr - nb;
        int p = atomicAdd(&cur[d], 1);
        csr_src[p] = (int)(pr >> 32);
    }
}

// ---------------- W prep: Wt[l][n][k] = bf16(W_l[k][n]) ----------------

__global__ void k_prep_w(const float* __restrict__ Wa, const float* __restrict__ Wb,
                         const float* __restrict__ Wc, ushort* __restrict__ Wt) {
    int idx = blockIdx.x * 256 + threadIdx.x;  // 3*16384
    int layer = idx >> 14;
    int r = idx & 16383;
    int nn = r >> 7, kk = r & 127;
    const float* W = (layer == 0) ? Wa : (layer == 1) ? Wb : Wc;
    Wt[idx] = f2bf(W[kk * 128 + nn]);
}

// ---------------- MFMA GEMM: xs[N,128](fp8) = dinv .* (X[N,128] @ W) ----------------

template<bool F32IN>
__launch_bounds__(256)
__global__ void k_gemm(const void* __restrict__ Xv, const ushort* __restrict__ Wt,
                       const float* __restrict__ dinv, unsigned char* __restrict__ C,
                       int N) {
    __shared__ ushort As[128][136];
    __shared__ ushort Ws[128][136];
    const int t = threadIdx.x;
    const int row0 = blockIdx.x * 128;

#pragma unroll
    for (int i = 0; i < 8; i++) {
        int c = t + i * 256;
        int r = c >> 4, c8 = (c & 15) * 8;
        *(bf16x8*)&Ws[r][c8] = *(const bf16x8*)&Wt[r * 128 + c8];
    }
    if (F32IN) {
        const float* X = (const float*)Xv;
#pragma unroll
        for (int i = 0; i < 8; i++) {
            int c = t + i * 256;
            int r = c >> 4, c8 = (c & 15) * 8;
            int row = row0 + r;
            bf16x8 pk = {0, 0, 0, 0, 0, 0, 0, 0};
            if (row < N) {
                const float* sp = X + (size_t)row * FDIM + c8;
                float4 u0 = *(const float4*)(sp);
                float4 u1 = *(const float4*)(sp + 4);
                pk[0] = (short)f2bf(u0.x); pk[1] = (short)f2bf(u0.y);
                pk[2] = (short)f2bf(u0.z); pk[3] = (short)f2bf(u0.w);
                pk[4] = (short)f2bf(u1.x); pk[5] = (short)f2bf(u1.y);
                pk[6] = (short)f2bf(u1.z); pk[7] = (short)f2bf(u1.w);
            }
            *(bf16x8*)&As[r][c8] = pk;
        }
    } else {
        const ushort* X = (const ushort*)Xv;
#pragma unroll
        for (int i = 0; i < 8; i++) {
            int c = t + i * 256;
            int r = c >> 4, c8 = (c & 15) * 8;
            int row = row0 + r;
            bf16x8 pk = {0, 0, 0, 0, 0, 0, 0, 0};
            if (row < N) pk = *(const bf16x8*)&X[(size_t)row * FDIM + c8];
            *(bf16x8*)&As[r][c8] = pk;
        }
    }
    __syncthreads();

    const int w = t >> 6, l = t & 63;
    const int m = l & 15, q = l >> 4;
    const int r0 = w * 32;

    bf16x8 a0[4], a1[4];
#pragma unroll
    for (int ks = 0; ks < 4; ks++) {
        a0[ks] = *(const bf16x8*)&As[r0 + m][ks * 32 + q * 8];
        a1[ks] = *(const bf16x8*)&As[r0 + 16 + m][ks * 32 + q * 8];
    }

    f32x4 acc0[8], acc1[8];
#pragma unroll
    for (int ct = 0; ct < 8; ct++) { acc0[ct] = {0, 0, 0, 0}; acc1[ct] = {0, 0, 0, 0}; }

#pragma unroll
    for (int ct = 0; ct < 8; ct++) {
#pragma unroll
        for (int ks = 0; ks < 4; ks++) {
            bf16x8 b = *(const bf16x8*)&Ws[ct * 16 + m][ks * 32 + q * 8];
            acc0[ct] = __builtin_amdgcn_mfma_f32_16x16x32_bf16(a0[ks], b, acc0[ct], 0, 0, 0);
            acc1[ct] = __builtin_amdgcn_mfma_f32_16x16x32_bf16(a1[ks], b, acc1[ct], 0, 0, 0);
        }
    }

    float dv0[4], dv1[4];
#pragma unroll
    for (int r = 0; r < 4; r++) {
        int row = row0 + r0 + q * 4 + r;
        dv0[r] = (row < N) ? dinv[row] : 0.f;
        dv1[r] = (row + 16 < N) ? dinv[row + 16] : 0.f;
    }
#pragma unroll
    for (int ct = 0; ct < 8; ct++) {
#pragma unroll
        for (int r = 0; r < 4; r++) {
            int row = row0 + r0 + q * 4 + r;
            if (row < N)
                C[(size_t)row * FDIM + ct * 16 + m] = f2fp8(acc0[ct][r] * dv0[r]);
            int row2 = row + 16;
            if (row2 < N)
                C[(size_t)row2 * FDIM + ct * 16 + m] = f2fp8(acc1[ct][r] * dv1[r]);
        }
    }
}

// ---------------- fused pull-aggregate, one node per wave64, fp8 gather ----------------
// 4 row-groups of 16 lanes; one load instruction fetches 4 src rows (512 B).
// out[n](bf16) = act(dinv[n]*(xs[n] + sum_e xs[csr_src[e]]) + b)

__launch_bounds__(256)
__global__ void k_aggregate(const unsigned char* __restrict__ xs8,
                            const int2* __restrict__ rowinfo,
                            const int* __restrict__ csr_src, const float* __restrict__ dinv,
                            const float* __restrict__ bias, ushort* __restrict__ out,
                            int N, int do_relu) {
    const int n = (blockIdx.x << 2) + (threadIdx.x >> 6);
    if (n >= N) return;
    const int l = threadIdx.x & 63;
    const int fl = l & 15;      // feature slot: features fl*8 .. fl*8+7
    const int grp = l >> 4;     // row group 0..3

    const uint2* xsr = (const uint2*)xs8;   // row r, slot fl at xsr[r*16 + fl]

    float acc[8] = {0, 0, 0, 0, 0, 0, 0, 0};
    // self term: only group 0 accumulates it
    if (grp == 0) {
        uint2 sv = xsr[(size_t)n * 16 + fl];
        fp8x8_add(sv, acc);
    }

    const int2 ri = rowinfo[n];
    const int beg = ri.x;
    const int deg = ri.y;

    for (int base = 0; base < deg; base += 64) {
        const int m = min(64, deg - base);
        int idx = 0;
        if (l < m) idx = csr_src[beg + base + l];  // coalesced
        int j = grp;
        if (j < m) {
            int s = __shfl(idx, j, 64);
            uint2 v = xsr[(size_t)s * 16 + fl];
#pragma unroll 2
            for (j += 4; j < m; j += 4) {
                int s2 = __shfl(idx, j, 64);
                uint2 v2 = xsr[(size_t)s2 * 16 + fl];   // prefetch next
                fp8x8_add(v, acc);
                v = v2;
            }
            fp8x8_add(v, acc);
        }
    }

    // reduce the 4 row-groups
#pragma unroll
    for (int k = 0; k < 8; k++) {
        acc[k] += __shfl_xor(acc[k], 16, 64);
        acc[k] += __shfl_xor(acc[k], 32, 64);
    }

    if (grp == 0) {
        const float d = dinv[n];
        const float4 b0 = ((const float4*)bias)[fl * 2];
        const float4 b1 = ((const float4*)bias)[fl * 2 + 1];
        const float bb[8] = {b0.x, b0.y, b0.z, b0.w, b1.x, b1.y, b1.z, b1.w};
        u16x8 o;
#pragma unroll
        for (int k = 0; k < 8; k++) {
            float v = d * acc[k] + bb[k];
            if (do_relu) v = fmaxf(v, 0.f);
            o[k] = f2bf(v);
        }
        ((u16x8*)out)[(size_t)n * 16 + fl] = o;
    }
}

// ---------------- two-stage pool ----------------

#define POOL_NODES 128

__launch_bounds__(128)
__global__ void k_pool(const ushort* __restrict__ x3, const int* __restrict__ batch,
                       float* __restrict__ sums, int N) {
    const int t = threadIdx.x;
    const int n0 = blockIdx.x * POOL_NODES;
    if (n0 >= N) return;
    const int n1 = (n0 + POOL_NODES < N) ? n0 + POOL_NODES : N;

    float acc = 0.f;
    int cur = batch[n0];
    for (int n = n0; n < n1; n++) {
        int g = batch[n];
        if (g != cur) {
            atomicAdd(&sums[cur * FDIM + t], acc);
            acc = 0.f;
            cur = g;
        }
        acc += bf2f(x3[(size_t)n * FDIM + t]);
    }
    atomicAdd(&sums[cur * FDIM + t], acc);
}

// ---------------- per-graph mean + MLP + LayerNorm ----------------

__launch_bounds__(128)
__global__ void k_final(const float* __restrict__ sums, const int* __restrict__ batch, int N,
                        const float* __restrict__ Wm1, const float* __restrict__ bm1,
                        const float* __restrict__ Wm2, const float* __restrict__ bm2,
                        const float* __restrict__ ln_g, const float* __restrict__ ln_b,
                        float* __restrict__ out) {
    const int g = blockIdx.x;
    const int t = threadIdx.x;

    int lo = 0, hi = N;
    while (lo < hi) { int mid = (lo + hi) >> 1; if (batch[mid] < g) lo = mid + 1; else hi = mid; }
    int lo2 = lo, hi2 = N;
    while (lo2 < hi2) { int mid = (lo2 + hi2) >> 1; if (batch[mid] < g + 1) lo2 = mid + 1; else hi2 = mid; }
    float cnt = (float)(lo2 - lo);

    float gl = sums[g * FDIM + t] / fmaxf(cnt, 1.0f);

    __shared__ float gbuf[FDIM];
    __shared__ float hbuf[FDIM];
    __shared__ float wsum[4];
    gbuf[t] = gl;
    __syncthreads();

    float h = bm1[t];
#pragma unroll 8
    for (int k = 0; k < FDIM; k++) h += gbuf[k] * Wm1[k * FDIM + t];
    h = fmaxf(h, 0.f);
    hbuf[t] = h;
    __syncthreads();

    float y = bm2[t];
#pragma unroll 8
    for (int k = 0; k < FDIM; k++) y += hbuf[k] * Wm2[k * FDIM + t];

    float s = y, s2 = y * y;
#pragma unroll
    for (int off = 32; off > 0; off >>= 1) {
        s += __shfl_down(s, off, 64);
        s2 += __shfl_down(s2, off, 64);
    }
    if ((t & 63) == 0) { wsum[t >> 6] = s; wsum[2 + (t >> 6)] = s2; }
    __syncthreads();
    float sum = wsum[0] + wsum[1];
    float sumsq = wsum[2] + wsum[3];
    float mu = sum * (1.0f / FDIM);
    float var = sumsq * (1.0f / FDIM) - mu * mu;
    float r = rsqrtf(var + LN_EPS);
    out[g * FDIM + t] = (y - mu) * r * ln_g[t] + ln_b[t];
}

// ---------------- launch ----------------

extern "C" void kernel_launch(void* const* d_in, const int* in_sizes, int n_in,
                              void* d_out, int out_size, void* d_ws, size_t ws_size,
                              hipStream_t stream) {
    const float* x_in  = (const float*)d_in[0];
    const int*   eidx  = (const int*)d_in[1];
    const int*   batch = (const int*)d_in[2];
    const float* W1 = (const float*)d_in[3];
    const float* b1 = (const float*)d_in[4];
    const float* W2 = (const float*)d_in[5];
    const float* b2 = (const float*)d_in[6];
    const float* W3 = (const float*)d_in[7];
    const float* b3 = (const float*)d_in[8];
    const float* Wm1 = (const float*)d_in[9];
    const float* bm1 = (const float*)d_in[10];
    const float* Wm2 = (const float*)d_in[11];
    const float* bm2 = (const float*)d_in[12];
    const float* ln_g = (const float*)d_in[13];
    const float* ln_b = (const float*)d_in[14];
    float* out = (float*)d_out;

    const int N = in_sizes[0] / FDIM;   // 100000
    const int E = in_sizes[1] / 2;      // 1600000
    const int G = out_size / FDIM;      // 64

    const int* src = eidx;
    const int* dst = eidx + E;

    const int nbkt = (N + BKT_NODES - 1) >> NBKT_SHIFT;        // 98

    // workspace layout
    char* p = (char*)d_ws;
    u64* bktA = (u64*)p;              p += (size_t)nbkt * BKT_CAP * 8;   // 25.7 MB
    unsigned char* B0q = (unsigned char*)p; p += (size_t)N * FDIM;       // 12.8 MB (fp8 xs)
    ushort* B1h = (ushort*)p;         p += (size_t)N * FDIM * 2;         // 25.6 MB (bf16 agg)
    int* csr_src = (int*)p;           p += (size_t)nbkt * BKT_CAP * 4;   // 12.8 MB
    int2* rowinfo = (int2*)p;         p += (size_t)N * 8;
    float* dinv = (float*)p;          p += (size_t)N * 4;
    ushort* Wt = (ushort*)p;          p += 3 * 16384 * 2;
    float* gsums = (float*)p;         p += (size_t)G * FDIM * 4;         // zeroed
    int* bcur = (int*)p;              p += MAXBKT * 4;                   // zeroed

    const int TPB = 256;
    dim3 blk(TPB);
    dim3 gAgg((N + 3) / 4);
    dim3 gTile((N + 127) / 128);
    const int nEb = (E + 2047) / 2048;

    // ---- build (gsums and bcur adjacent -> one memset) ----
    hipMemsetAsync(gsums, 0, (size_t)G * FDIM * 4 + MAXBKT * 4, stream);
    k_bkt_scatter<<<dim3(nEb), blk, 0, stream>>>(src, dst, bcur, bktA, E, nbkt);
    k_build<<<dim3(nbkt), dim3(1024), 0, stream>>>(bktA, bcur, rowinfo, dinv, csr_src, N);
    k_prep_w<<<dim3(192), blk, 0, stream>>>(W1, W2, W3, Wt);

    // ---- layer 1 (fp32 input) ----
    k_gemm<true><<<gTile, blk, 0, stream>>>(x_in, Wt, dinv, B0q, N);
    k_aggregate<<<gAgg, blk, 0, stream>>>(B0q, rowinfo, csr_src, dinv, b1, B1h, N, 1);

    // ---- layer 2 ----
    k_gemm<false><<<gTile, blk, 0, stream>>>(B1h, Wt + 16384, dinv, B0q, N);
    k_aggregate<<<gAgg, blk, 0, stream>>>(B0q, rowinfo, csr_src, dinv, b2, B1h, N, 1);

    // ---- layer 3 (no relu) ----
    k_gemm<false><<<gTile, blk, 0, stream>>>(B1h, Wt + 32768, dinv, B0q, N);
    k_aggregate<<<gAgg, blk, 0, stream>>>(B0q, rowinfo, csr_src, dinv, b3, B1h, N, 0);

    // ---- pool + MLP + LN ----
    k_pool<<<dim3((N + POOL_NODES - 1) / POOL_NODES), dim3(FDIM), 0, stream>>>(B1h, batch, gsums, N);
    k_final<<<dim3(G), dim3(FDIM), 0, stream>>>(gsums, batch, N, Wm1, bm1, Wm2, bm2,
                                                ln_g, ln_b, out);
}

// Round 11
// 478.466 us; speedup vs baseline: 1.6480x; 1.0044x over previous
//
#include <hip/hip_runtime.h>

#define FDIM 128
#define LN_EPS 1e-5f
#define NBKT_SHIFT 10          // 1024 nodes per bucket
#define BKT_NODES 1024
#define MAXBKT 128             // supports N <= 131072 (src fits 17 bits)
#define CAP_SHIFT 15           // 32768 edge capacity per bucket (mean 16384, ~8 sigma)
#define BKT_CAP 32768

typedef short bf16x8 __attribute__((ext_vector_type(8)));
typedef float f32x4 __attribute__((ext_vector_type(4)));
typedef float f32x2 __attribute__((ext_vector_type(2)));
typedef ushort u16x8 __attribute__((ext_vector_type(8)));
typedef unsigned long long u64;

static __device__ __forceinline__ ushort f2bf(float f) {
    union { float f; unsigned u; } v; v.f = f;
    unsigned r = v.u + 0x7FFFu + ((v.u >> 16) & 1u);  // RNE
    return (ushort)(r >> 16);
}
static __device__ __forceinline__ float bf2f(ushort h) {
    union { unsigned u; float f; } v; v.u = ((unsigned)h) << 16;
    return v.f;
}
// fp8 e4m3 (OCP on gfx950) encode/decode via HW converts
static __device__ __forceinline__ unsigned char f2fp8(float f) {
    return (unsigned char)__builtin_amdgcn_cvt_pk_fp8_f32(f, f, 0u, false);
}
// decode 8 fp8 and accumulate into 4 packed f32x2 (v_pk_add_f32 path)
static __device__ __forceinline__ void fp8x8_add(uint2 w, f32x2* acc) {
    acc[0] += __builtin_amdgcn_cvt_pk_f32_fp8(w.x, false);
    acc[1] += __builtin_amdgcn_cvt_pk_f32_fp8(w.x, true);
    acc[2] += __builtin_amdgcn_cvt_pk_f32_fp8(w.y, false);
    acc[3] += __builtin_amdgcn_cvt_pk_f32_fp8(w.y, true);
}

// ---------------- bucketed edge scatter (fixed-capacity buckets) ----------------
// Packs (src,local_dst) into ONE u32: src<<10 | (dst & 1023). 2-way replicated
// LDS histograms/cursors halve LDS-atomic serialization.

__launch_bounds__(256)
__global__ void k_bkt_scatter(const int* __restrict__ src, const int* __restrict__ dst,
                              int* __restrict__ bcur, unsigned* __restrict__ bktA,
                              int E, int nbkt) {
    __shared__ int h[2][MAXBKT], lbase[2][MAXBKT], lcur[2][MAXBKT];
    const int t = threadIdx.x;
    const int half = t >> 7;
    for (int i = t; i < 2 * MAXBKT; i += 256) ((int*)h)[i] = 0;
    __syncthreads();
    const int E4 = E >> 2;   // E multiple of 4
    const int4* s4p = (const int4*)src;
    const int4* d4p = (const int4*)dst;
    int4 sv[2], dv[2]; bool ok[2];
#pragma unroll
    for (int r = 0; r < 2; r++) {
        int i4 = blockIdx.x * 512 + r * 256 + t;
        ok[r] = (i4 < E4);
        if (ok[r]) {
            sv[r] = s4p[i4]; dv[r] = d4p[i4];
            atomicAdd(&h[half][dv[r].x >> NBKT_SHIFT], 1);
            atomicAdd(&h[half][dv[r].y >> NBKT_SHIFT], 1);
            atomicAdd(&h[half][dv[r].z >> NBKT_SHIFT], 1);
            atomicAdd(&h[half][dv[r].w >> NBKT_SHIFT], 1);
        }
    }
    __syncthreads();
    for (int i = t; i < 2 * nbkt; i += 256) {
        const int hh = (i >= nbkt) ? 1 : 0;
        const int b = hh ? (i - nbkt) : i;
        const int c = h[hh][b];
        lbase[hh][b] = c ? ((b << CAP_SHIFT) + atomicAdd(&bcur[b], c)) : 0;
        lcur[hh][b] = 0;
    }
    __syncthreads();
#pragma unroll
    for (int r = 0; r < 2; r++) {
        if (!ok[r]) continue;
        int ss[4] = {sv[r].x, sv[r].y, sv[r].z, sv[r].w};
        int dd[4] = {dv[r].x, dv[r].y, dv[r].z, dv[r].w};
#pragma unroll
        for (int j = 0; j < 4; j++) {
            int b = dd[j] >> NBKT_SHIFT;
            int p = atomicAdd(&lcur[half][b], 1);
            bktA[(size_t)lbase[half][b] + p] =
                ((unsigned)ss[j] << NBKT_SHIFT) | (unsigned)(dd[j] & (BKT_NODES - 1));
        }
    }
}

// merged per-bucket: degree count -> wave-level scan -> rowinfo/dinv -> CSR fill

__launch_bounds__(1024)
__global__ void k_build(const unsigned* __restrict__ bktA, const int* __restrict__ bcur,
                        int2* __restrict__ rowinfo, float* __restrict__ dinv,
                        int* __restrict__ csr_src, int N) {
    __shared__ int cnt[BKT_NODES];
    __shared__ int cur[BKT_NODES];
    __shared__ int wpart[16], wbase[16];
    const int t = threadIdx.x;
    const int b = blockIdx.x;
    const int nb = b << NBKT_SHIFT;
    cnt[t] = 0;
    __syncthreads();
    const int beg = b << CAP_SHIFT;
    const int end = beg + bcur[b];
    for (int i = beg + t; i < end; i += 1024)
        atomicAdd(&cnt[bktA[i] & (BKT_NODES - 1)], 1);
    __syncthreads();
    const int lane = t & 63, wv = t >> 6;
    const int my = cnt[t];
    int x = my;
#pragma unroll
    for (int off = 1; off < 64; off <<= 1) {
        int y = __shfl_up(x, off, 64);
        if (lane >= off) x += y;
    }
    if (lane == 63) wpart[wv] = x;
    __syncthreads();
    if (t == 0) {
        int s = 0;
        for (int w = 0; w < 16; w++) { int tmp = wpart[w]; wbase[w] = s; s += tmp; }
    }
    __syncthreads();
    const int incl = x + wbase[wv];
    const int rbeg = beg + incl - my;   // exclusive start within padded CSR
    cur[t] = rbeg;
    const int n = nb + t;
    if (n < N) {
        rowinfo[n] = make_int2(rbeg, my);
        dinv[n] = rsqrtf((float)(my + 1));  // +1 self-loop
    }
    __syncthreads();
    for (int i = beg + t; i < end; i += 1024) {
        unsigned pr = bktA[i];
        int d = pr & (BKT_NODES - 1);
        int p = atomicAdd(&cur[d], 1);
        csr_src[p] = (int)(pr >> NBKT_SHIFT);
    }
}

// ---------------- W prep: Wt[l][n][k] = bf16(W_l[k][n]) ----------------

__global__ void k_prep_w(const float* __restrict__ Wa, const float* __restrict__ Wb,
                         const float* __restrict__ Wc, ushort* __restrict__ Wt) {
    int idx = blockIdx.x * 256 + threadIdx.x;  // 3*16384
    int layer = idx >> 14;
    int r = idx & 16383;
    int nn = r >> 7, kk = r & 127;
    const float* W = (layer == 0) ? Wa : (layer == 1) ? Wb : Wc;
    Wt[idx] = f2bf(W[kk * 128 + nn]);
}

// ---------------- MFMA GEMM: xs[N,128](fp8) = dinv .* (X[N,128] @ W) ----------------

template<bool F32IN>
__launch_bounds__(256)
__global__ void k_gemm(const void* __restrict__ Xv, const ushort* __restrict__ Wt,
                       const float* __restrict__ dinv, unsigned char* __restrict__ C,
                       int N) {
    __shared__ ushort As[128][136];
    __shared__ ushort Ws[128][136];
    const int t = threadIdx.x;
    const int row0 = blockIdx.x * 128;

#pragma unroll
    for (int i = 0; i < 8; i++) {
        int c = t + i * 256;
        int r = c >> 4, c8 = (c & 15) * 8;
        *(bf16x8*)&Ws[r][c8] = *(const bf16x8*)&Wt[r * 128 + c8];
    }
    if (F32IN) {
        const float* X = (const float*)Xv;
#pragma unroll
        for (int i = 0; i < 8; i++) {
            int c = t + i * 256;
            int r = c >> 4, c8 = (c & 15) * 8;
            int row = row0 + r;
            bf16x8 pk = {0, 0, 0, 0, 0, 0, 0, 0};
            if (row < N) {
                const float* sp = X + (size_t)row * FDIM + c8;
                float4 u0 = *(const float4*)(sp);
                float4 u1 = *(const float4*)(sp + 4);
                pk[0] = (short)f2bf(u0.x); pk[1] = (short)f2bf(u0.y);
                pk[2] = (short)f2bf(u0.z); pk[3] = (short)f2bf(u0.w);
                pk[4] = (short)f2bf(u1.x); pk[5] = (short)f2bf(u1.y);
                pk[6] = (short)f2bf(u1.z); pk[7] = (short)f2bf(u1.w);
            }
            *(bf16x8*)&As[r][c8] = pk;
        }
    } else {
        const ushort* X = (const ushort*)Xv;
#pragma unroll
        for (int i = 0; i < 8; i++) {
            int c = t + i * 256;
            int r = c >> 4, c8 = (c & 15) * 8;
            int row = row0 + r;
            bf16x8 pk = {0, 0, 0, 0, 0, 0, 0, 0};
            if (row < N) pk = *(const bf16x8*)&X[(size_t)row * FDIM + c8];
            *(bf16x8*)&As[r][c8] = pk;
        }
    }
    __syncthreads();

    const int w = t >> 6, l = t & 63;
    const int m = l & 15, q = l >> 4;
    const int r0 = w * 32;

    bf16x8 a0[4], a1[4];
#pragma unroll
    for (int ks = 0; ks < 4; ks++) {
        a0[ks] = *(const bf16x8*)&As[r0 + m][ks * 32 + q * 8];
        a1[ks] = *(const bf16x8*)&As[r0 + 16 + m][ks * 32 + q * 8];
    }

    f32x4 acc0[8], acc1[8];
#pragma unroll
    for (int ct = 0; ct < 8; ct++) { acc0[ct] = {0, 0, 0, 0}; acc1[ct] = {0, 0, 0, 0}; }

#pragma unroll
    for (int ct = 0; ct < 8; ct++) {
#pragma unroll
        for (int ks = 0; ks < 4; ks++) {
            bf16x8 b = *(const bf16x8*)&Ws[ct * 16 + m][ks * 32 + q * 8];
            acc0[ct] = __builtin_amdgcn_mfma_f32_16x16x32_bf16(a0[ks], b, acc0[ct], 0, 0, 0);
            acc1[ct] = __builtin_amdgcn_mfma_f32_16x16x32_bf16(a1[ks], b, acc1[ct], 0, 0, 0);
        }
    }

    float dv0[4], dv1[4];
#pragma unroll
    for (int r = 0; r < 4; r++) {
        int row = row0 + r0 + q * 4 + r;
        dv0[r] = (row < N) ? dinv[row] : 0.f;
        dv1[r] = (row + 16 < N) ? dinv[row + 16] : 0.f;
    }
#pragma unroll
    for (int ct = 0; ct < 8; ct++) {
#pragma unroll
        for (int r = 0; r < 4; r++) {
            int row = row0 + r0 + q * 4 + r;
            if (row < N)
                C[(size_t)row * FDIM + ct * 16 + m] = f2fp8(acc0[ct][r] * dv0[r]);
            int row2 = row + 16;
            if (row2 < N)
                C[(size_t)row2 * FDIM + ct * 16 + m] = f2fp8(acc1[ct][r] * dv1[r]);
        }
    }
}

// ---------------- fused pull-aggregate, one node per wave64, fp8 gather ----------------
// 4 row-groups of 16 lanes; one load instruction fetches 4 src rows (512 B).
// Packed f32x2 accumulate. out[n](bf16) = act(dinv[n]*(xs[n]+sum)+b)

__launch_bounds__(256)
__global__ void k_aggregate(const unsigned char* __restrict__ xs8,
                            const int2* __restrict__ rowinfo,
                            const int* __restrict__ csr_src, const float* __restrict__ dinv,
                            const float* __restrict__ bias, ushort* __restrict__ out,
                            int N, int do_relu) {
    const int n = (blockIdx.x << 2) + (threadIdx.x >> 6);
    if (n >= N) return;
    const int l = threadIdx.x & 63;
    const int fl = l & 15;      // feature slot: features fl*8 .. fl*8+7
    const int grp = l >> 4;     // row group 0..3

    const uint2* xsr = (const uint2*)xs8;   // row r, slot fl at xsr[r*16 + fl]

    f32x2 acc[4] = {{0, 0}, {0, 0}, {0, 0}, {0, 0}};
    // self term: only group 0 accumulates it
    if (grp == 0) {
        uint2 sv = xsr[(size_t)n * 16 + fl];
        fp8x8_add(sv, acc);
    }

    const int2 ri = rowinfo[n];
    const int beg = ri.x;
    const int deg = ri.y;

    for (int base = 0; base < deg; base += 64) {
        const int m = min(64, deg - base);
        int idx = 0;
        if (l < m) idx = csr_src[beg + base + l];  // coalesced
        int j = grp;
        if (j < m) {
            int s = __shfl(idx, j, 64);
            uint2 v = xsr[(size_t)s * 16 + fl];
#pragma unroll 2
            for (j += 4; j < m; j += 4) {
                int s2 = __shfl(idx, j, 64);
                uint2 v2 = xsr[(size_t)s2 * 16 + fl];   // prefetch next
                fp8x8_add(v, acc);
                v = v2;
            }
            fp8x8_add(v, acc);
        }
    }

    // reduce the 4 row-groups (component-wise shuffles)
    float a[8] = {acc[0][0], acc[0][1], acc[1][0], acc[1][1],
                  acc[2][0], acc[2][1], acc[3][0], acc[3][1]};
#pragma unroll
    for (int k = 0; k < 8; k++) {
        a[k] += __shfl_xor(a[k], 16, 64);
        a[k] += __shfl_xor(a[k], 32, 64);
    }

    if (grp == 0) {
        const float d = dinv[n];
        const float4 b0 = ((const float4*)bias)[fl * 2];
        const float4 b1 = ((const float4*)bias)[fl * 2 + 1];
        const float bb[8] = {b0.x, b0.y, b0.z, b0.w, b1.x, b1.y, b1.z, b1.w};
        u16x8 o;
#pragma unroll
        for (int k = 0; k < 8; k++) {
            float v = d * a[k] + bb[k];
            if (do_relu) v = fmaxf(v, 0.f);
            o[k] = f2bf(v);
        }
        ((u16x8*)out)[(size_t)n * 16 + fl] = o;
    }
}

// ---------------- two-stage pool ----------------

#define POOL_NODES 128

__launch_bounds__(128)
__global__ void k_pool(const ushort* __restrict__ x3, const int* __restrict__ batch,
                       float* __restrict__ sums, int N) {
    const int t = threadIdx.x;
    const int n0 = blockIdx.x * POOL_NODES;
    if (n0 >= N) return;
    const int n1 = (n0 + POOL_NODES < N) ? n0 + POOL_NODES : N;

    float acc = 0.f;
    int cur = batch[n0];
    for (int n = n0; n < n1; n++) {
        int g = batch[n];
        if (g != cur) {
            atomicAdd(&sums[cur * FDIM + t], acc);
            acc = 0.f;
            cur = g;
        }
        acc += bf2f(x3[(size_t)n * FDIM + t]);
    }
    atomicAdd(&sums[cur * FDIM + t], acc);
}

// ---------------- per-graph mean + MLP + LayerNorm ----------------

__launch_bounds__(128)
__global__ void k_final(const float* __restrict__ sums, const int* __restrict__ batch, int N,
                        const float* __restrict__ Wm1, const float* __restrict__ bm1,
                        const float* __restrict__ Wm2, const float* __restrict__ bm2,
                        const float* __restrict__ ln_g, const float* __restrict__ ln_b,
                        float* __restrict__ out) {
    const int g = blockIdx.x;
    const int t = threadIdx.x;

    int lo = 0, hi = N;
    while (lo < hi) { int mid = (lo + hi) >> 1; if (batch[mid] < g) lo = mid + 1; else hi = mid; }
    int lo2 = lo, hi2 = N;
    while (lo2 < hi2) { int mid = (lo2 + hi2) >> 1; if (batch[mid] < g + 1) lo2 = mid + 1; else hi2 = mid; }
    float cnt = (float)(lo2 - lo);

    float gl = sums[g * FDIM + t] / fmaxf(cnt, 1.0f);

    __shared__ float gbuf[FDIM];
    __shared__ float hbuf[FDIM];
    __shared__ float wsum[4];
    gbuf[t] = gl;
    __syncthreads();

    float h = bm1[t];
#pragma unroll 8
    for (int k = 0; k < FDIM; k++) h += gbuf[k] * Wm1[k * FDIM + t];
    h = fmaxf(h, 0.f);
    hbuf[t] = h;
    __syncthreads();

    float y = bm2[t];
#pragma unroll 8
    for (int k = 0; k < FDIM; k++) y += hbuf[k] * Wm2[k * FDIM + t];

    float s = y, s2 = y * y;
#pragma unroll
    for (int off = 32; off > 0; off >>= 1) {
        s += __shfl_down(s, off, 64);
        s2 += __shfl_down(s2, off, 64);
    }
    if ((t & 63) == 0) { wsum[t >> 6] = s; wsum[2 + (t >> 6)] = s2; }
    __syncthreads();
    float sum = wsum[0] + wsum[1];
    float sumsq = wsum[2] + wsum[3];
    float mu = sum * (1.0f / FDIM);
    float var = sumsq * (1.0f / FDIM) - mu * mu;
    float r = rsqrtf(var + LN_EPS);
    out[g * FDIM + t] = (y - mu) * r * ln_g[t] + ln_b[t];
}

// ---------------- launch ----------------

extern "C" void kernel_launch(void* const* d_in, const int* in_sizes, int n_in,
                              void* d_out, int out_size, void* d_ws, size_t ws_size,
                              hipStream_t stream) {
    const float* x_in  = (const float*)d_in[0];
    const int*   eidx  = (const int*)d_in[1];
    const int*   batch = (const int*)d_in[2];
    const float* W1 = (const float*)d_in[3];
    const float* b1 = (const float*)d_in[4];
    const float* W2 = (const float*)d_in[5];
    const float* b2 = (const float*)d_in[6];
    const float* W3 = (const float*)d_in[7];
    const float* b3 = (const float*)d_in[8];
    const float* Wm1 = (const float*)d_in[9];
    const float* bm1 = (const float*)d_in[10];
    const float* Wm2 = (const float*)d_in[11];
    const float* bm2 = (const float*)d_in[12];
    const float* ln_g = (const float*)d_in[13];
    const float* ln_b = (const float*)d_in[14];
    float* out = (float*)d_out;

    const int N = in_sizes[0] / FDIM;   // 100000
    const int E = in_sizes[1] / 2;      // 1600000
    const int G = out_size / FDIM;      // 64

    const int* src = eidx;
    const int* dst = eidx + E;

    const int nbkt = (N + BKT_NODES - 1) >> NBKT_SHIFT;        // 98

    // workspace layout
    char* p = (char*)d_ws;
    unsigned* bktA = (unsigned*)p;    p += (size_t)nbkt * BKT_CAP * 4;   // 12.8 MB (packed)
    unsigned char* B0q = (unsigned char*)p; p += (size_t)N * FDIM;       // 12.8 MB (fp8 xs)
    ushort* B1h = (ushort*)p;         p += (size_t)N * FDIM * 2;         // 25.6 MB (bf16 agg)
    int* csr_src = (int*)p;           p += (size_t)nbkt * BKT_CAP * 4;   // 12.8 MB
    int2* rowinfo = (int2*)p;         p += (size_t)N * 8;
    float* dinv = (float*)p;          p += (size_t)N * 4;
    ushort* Wt = (ushort*)p;          p += 3 * 16384 * 2;
    float* gsums = (float*)p;         p += (size_t)G * FDIM * 4;         // zeroed
    int* bcur = (int*)p;              p += MAXBKT * 4;                   // zeroed

    const int TPB = 256;
    dim3 blk(TPB);
    dim3 gAgg((N + 3) / 4);
    dim3 gTile((N + 127) / 128);
    const int nEb = (E + 2047) / 2048;

    // ---- build (gsums and bcur adjacent -> one memset) ----
    k_prep_w<<<dim3(192), blk, 0, stream>>>(W1, W2, W3, Wt);
    hipMemsetAsync(gsums, 0, (size_t)G * FDIM * 4 + MAXBKT * 4, stream);
    k_bkt_scatter<<<dim3(nEb), blk, 0, stream>>>(src, dst, bcur, bktA, E, nbkt);
    k_build<<<dim3(nbkt), dim3(1024), 0, stream>>>(bktA, bcur, rowinfo, dinv, csr_src, N);

    // ---- layer 1 (fp32 input) ----
    k_gemm<true><<<gTile, blk, 0, stream>>>(x_in, Wt, dinv, B0q, N);
    k_aggregate<<<gAgg, blk, 0, stream>>>(B0q, rowinfo, csr_src, dinv, b1, B1h, N, 1);

    // ---- layer 2 ----
    k_gemm<false><<<gTile, blk, 0, stream>>>(B1h, Wt + 16384, dinv, B0q, N);
    k_aggregate<<<gAgg, blk, 0, stream>>>(B0q, rowinfo, csr_src, dinv, b2, B1h, N, 1);

    // ---- layer 3 (no relu) ----
    k_gemm<false><<<gTile, blk, 0, stream>>>(B1h, Wt + 32768, dinv, B0q, N);
    k_aggregate<<<gAgg, blk, 0, stream>>>(B0q, rowinfo, csr_src, dinv, b3, B1h, N, 0);

    // ---- pool + MLP + LN ----
    k_pool<<<dim3((N + POOL_NODES - 1) / POOL_NODES), dim3(FDIM), 0, stream>>>(B1h, batch, gsums, N);
    k_final<<<dim3(G), dim3(FDIM), 0, stream>>>(gsums, batch, N, Wm1, bm1, Wm2, bm2,
                                                ln_g, ln_b, out);
}

// Round 12
// 437.115 us; speedup vs baseline: 1.8039x; 1.0946x over previous
//
#include <hip/hip_runtime.h>

#define FDIM 128
#define LN_EPS 1e-5f
#define NBKT_SHIFT 10          // 1024 nodes per bucket
#define BKT_NODES 1024
#define MAXBKT 128             // supports N <= 131072 (src fits 17 bits packed)
#define CAP_SHIFT 15           // 32768 edge capacity per bucket (mean 16384, ~8 sigma)
#define BKT_CAP 32768

typedef short bf16x8 __attribute__((ext_vector_type(8)));
typedef float f32x4 __attribute__((ext_vector_type(4)));
typedef float f32x2 __attribute__((ext_vector_type(2)));
typedef ushort u16x8 __attribute__((ext_vector_type(8)));
typedef unsigned long long u64;

static __device__ __forceinline__ ushort f2bf(float f) {
    union { float f; unsigned u; } v; v.f = f;
    unsigned r = v.u + 0x7FFFu + ((v.u >> 16) & 1u);  // RNE
    return (ushort)(r >> 16);
}
static __device__ __forceinline__ float bf2f(ushort h) {
    union { unsigned u; float f; } v; v.u = ((unsigned)h) << 16;
    return v.f;
}
// fp8 e4m3 (OCP on gfx950) encode/decode via HW converts
static __device__ __forceinline__ unsigned char f2fp8(float f) {
    return (unsigned char)__builtin_amdgcn_cvt_pk_fp8_f32(f, f, 0u, false);
}
static __device__ __forceinline__ void fp8x8_add(uint2 w, f32x2* acc) {
    acc[0] += __builtin_amdgcn_cvt_pk_f32_fp8(w.x, false);
    acc[1] += __builtin_amdgcn_cvt_pk_f32_fp8(w.x, true);
    acc[2] += __builtin_amdgcn_cvt_pk_f32_fp8(w.y, false);
    acc[3] += __builtin_amdgcn_cvt_pk_f32_fp8(w.y, true);
}

// ---------------- bucketed edge scatter (fixed-capacity buckets) ----------------
// 4096 edges/block. Packs (src,local_dst) into one u32: src<<10 | (dst & 1023).
// 2-way replicated LDS histograms/cursors halve LDS-atomic serialization.

__launch_bounds__(256)
__global__ void k_bkt_scatter(const int* __restrict__ src, const int* __restrict__ dst,
                              int* __restrict__ bcur, unsigned* __restrict__ bktA,
                              int E, int nbkt) {
    __shared__ int h[2][MAXBKT], lbase[2][MAXBKT], lcur[2][MAXBKT];
    const int t = threadIdx.x;
    const int half = t >> 7;
    for (int i = t; i < 2 * MAXBKT; i += 256) ((int*)h)[i] = 0;
    __syncthreads();
    const int E4 = E >> 2;   // E multiple of 4
    const int4* s4p = (const int4*)src;
    const int4* d4p = (const int4*)dst;
    int4 sv[4], dv[4]; bool ok[4];
#pragma unroll
    for (int r = 0; r < 4; r++) {
        int i4 = blockIdx.x * 1024 + r * 256 + t;
        ok[r] = (i4 < E4);
        if (ok[r]) {
            sv[r] = s4p[i4]; dv[r] = d4p[i4];
            atomicAdd(&h[half][dv[r].x >> NBKT_SHIFT], 1);
            atomicAdd(&h[half][dv[r].y >> NBKT_SHIFT], 1);
            atomicAdd(&h[half][dv[r].z >> NBKT_SHIFT], 1);
            atomicAdd(&h[half][dv[r].w >> NBKT_SHIFT], 1);
        }
    }
    __syncthreads();
    for (int i = t; i < 2 * nbkt; i += 256) {
        const int hh = (i >= nbkt) ? 1 : 0;
        const int b = hh ? (i - nbkt) : i;
        const int c = h[hh][b];
        lbase[hh][b] = c ? ((b << CAP_SHIFT) + atomicAdd(&bcur[b], c)) : 0;
        lcur[hh][b] = 0;
    }
    __syncthreads();
#pragma unroll
    for (int r = 0; r < 4; r++) {
        if (!ok[r]) continue;
        int ss[4] = {sv[r].x, sv[r].y, sv[r].z, sv[r].w};
        int dd[4] = {dv[r].x, dv[r].y, dv[r].z, dv[r].w};
#pragma unroll
        for (int j = 0; j < 4; j++) {
            int b = dd[j] >> NBKT_SHIFT;
            int p = atomicAdd(&lcur[half][b], 1);
            bktA[(size_t)lbase[half][b] + p] =
                ((unsigned)ss[j] << NBKT_SHIFT) | (unsigned)(dd[j] & (BKT_NODES - 1));
        }
    }
}

// merged per-bucket: degree count -> wave-level scan -> rowinfo/dinv -> CSR fill

__launch_bounds__(1024)
__global__ void k_build(const unsigned* __restrict__ bktA, const int* __restrict__ bcur,
                        int2* __restrict__ rowinfo, float* __restrict__ dinv,
                        int* __restrict__ csr_src, int N) {
    __shared__ int cnt[BKT_NODES];
    __shared__ int cur[BKT_NODES];
    __shared__ int wpart[16], wbase[16];
    const int t = threadIdx.x;
    const int b = blockIdx.x;
    const int nb = b << NBKT_SHIFT;
    cnt[t] = 0;
    __syncthreads();
    const int beg = b << CAP_SHIFT;
    const int end = beg + bcur[b];
    for (int i = beg + t; i < end; i += 1024)
        atomicAdd(&cnt[bktA[i] & (BKT_NODES - 1)], 1);
    __syncthreads();
    const int lane = t & 63, wv = t >> 6;
    const int my = cnt[t];
    int x = my;
#pragma unroll
    for (int off = 1; off < 64; off <<= 1) {
        int y = __shfl_up(x, off, 64);
        if (lane >= off) x += y;
    }
    if (lane == 63) wpart[wv] = x;
    __syncthreads();
    if (t == 0) {
        int s = 0;
        for (int w = 0; w < 16; w++) { int tmp = wpart[w]; wbase[w] = s; s += tmp; }
    }
    __syncthreads();
    const int incl = x + wbase[wv];
    const int rbeg = beg + incl - my;   // exclusive start within padded CSR
    cur[t] = rbeg;
    const int n = nb + t;
    if (n < N) {
        rowinfo[n] = make_int2(rbeg, my);
        dinv[n] = rsqrtf((float)(my + 1));  // +1 self-loop
    }
    __syncthreads();
    for (int i = beg + t; i < end; i += 1024) {
        unsigned pr = bktA[i];
        int d = pr & (BKT_NODES - 1);
        int p = atomicAdd(&cur[d], 1);
        csr_src[p] = (int)(pr >> NBKT_SHIFT);
    }
}

// ---------------- W prep: Wt[l][n][k] = bf16(W_l[k][n]) ----------------

__global__ void k_prep_w(const float* __restrict__ Wa, const float* __restrict__ Wb,
                         const float* __restrict__ Wc, ushort* __restrict__ Wt) {
    int idx = blockIdx.x * 256 + threadIdx.x;  // 3*16384
    int layer = idx >> 14;
    int r = idx & 16383;
    int nn = r >> 7, kk = r & 127;
    const float* W = (layer == 0) ? Wa : (layer == 1) ? Wb : Wc;
    Wt[idx] = f2bf(W[kk * 128 + nn]);
}

// ---------------- MFMA GEMM: xs[N,128](fp8) = dinv .* (X[N,128] @ W) ----------------
// fp8 output staged through LDS -> coalesced dwordx4 global stores.

template<bool F32IN>
__launch_bounds__(256)
__global__ void k_gemm(const void* __restrict__ Xv, const ushort* __restrict__ Wt,
                       const float* __restrict__ dinv, unsigned char* __restrict__ C,
                       int N) {
    __shared__ __align__(16) ushort As[128][136];
    __shared__ ushort Ws[128][136];
    const int t = threadIdx.x;
    const int row0 = blockIdx.x * 128;

#pragma unroll
    for (int i = 0; i < 8; i++) {
        int c = t + i * 256;
        int r = c >> 4, c8 = (c & 15) * 8;
        *(bf16x8*)&Ws[r][c8] = *(const bf16x8*)&Wt[r * 128 + c8];
    }
    if (F32IN) {
        const float* X = (const float*)Xv;
#pragma unroll
        for (int i = 0; i < 8; i++) {
            int c = t + i * 256;
            int r = c >> 4, c8 = (c & 15) * 8;
            int row = row0 + r;
            bf16x8 pk = {0, 0, 0, 0, 0, 0, 0, 0};
            if (row < N) {
                const float* sp = X + (size_t)row * FDIM + c8;
                float4 u0 = *(const float4*)(sp);
                float4 u1 = *(const float4*)(sp + 4);
                pk[0] = (short)f2bf(u0.x); pk[1] = (short)f2bf(u0.y);
                pk[2] = (short)f2bf(u0.z); pk[3] = (short)f2bf(u0.w);
                pk[4] = (short)f2bf(u1.x); pk[5] = (short)f2bf(u1.y);
                pk[6] = (short)f2bf(u1.z); pk[7] = (short)f2bf(u1.w);
            }
            *(bf16x8*)&As[r][c8] = pk;
        }
    } else {
        const ushort* X = (const ushort*)Xv;
#pragma unroll
        for (int i = 0; i < 8; i++) {
            int c = t + i * 256;
            int r = c >> 4, c8 = (c & 15) * 8;
            int row = row0 + r;
            bf16x8 pk = {0, 0, 0, 0, 0, 0, 0, 0};
            if (row < N) pk = *(const bf16x8*)&X[(size_t)row * FDIM + c8];
            *(bf16x8*)&As[r][c8] = pk;
        }
    }
    __syncthreads();

    const int w = t >> 6, l = t & 63;
    const int m = l & 15, q = l >> 4;
    const int r0 = w * 32;

    bf16x8 a0[4], a1[4];
#pragma unroll
    for (int ks = 0; ks < 4; ks++) {
        a0[ks] = *(const bf16x8*)&As[r0 + m][ks * 32 + q * 8];
        a1[ks] = *(const bf16x8*)&As[r0 + 16 + m][ks * 32 + q * 8];
    }

    f32x4 acc0[8], acc1[8];
#pragma unroll
    for (int ct = 0; ct < 8; ct++) { acc0[ct] = {0, 0, 0, 0}; acc1[ct] = {0, 0, 0, 0}; }

#pragma unroll
    for (int ct = 0; ct < 8; ct++) {
#pragma unroll
        for (int ks = 0; ks < 4; ks++) {
            bf16x8 b = *(const bf16x8*)&Ws[ct * 16 + m][ks * 32 + q * 8];
            acc0[ct] = __builtin_amdgcn_mfma_f32_16x16x32_bf16(a0[ks], b, acc0[ct], 0, 0, 0);
            acc1[ct] = __builtin_amdgcn_mfma_f32_16x16x32_bf16(a1[ks], b, acc1[ct], 0, 0, 0);
        }
    }

    float dv0[4], dv1[4];
#pragma unroll
    for (int r = 0; r < 4; r++) {
        int row = row0 + r0 + q * 4 + r;
        dv0[r] = (row < N) ? dinv[row] : 0.f;
        dv1[r] = (row + 16 < N) ? dinv[row + 16] : 0.f;
    }

    // stage fp8 tile (16 KB) into LDS (reuse As; all LDS reads are done)
    __syncthreads();
    char* Ab = (char*)&As[0][0];
#pragma unroll
    for (int ct = 0; ct < 8; ct++) {
#pragma unroll
        for (int r = 0; r < 4; r++) {
            int rl = r0 + q * 4 + r;
            Ab[rl * 128 + ct * 16 + m] = (char)f2fp8(acc0[ct][r] * dv0[r]);
            Ab[(rl + 16) * 128 + ct * 16 + m] = (char)f2fp8(acc1[ct][r] * dv1[r]);
        }
    }
    __syncthreads();
    const uint4* As4 = (const uint4*)Ab;
#pragma unroll
    for (int i = 0; i < 4; i++) {
        int c = t + i * 256;        // 1024 chunks of 16 B
        int row = c >> 3;           // 8 chunks per row
        int col = (c & 7) * 16;
        int grow = row0 + row;
        if (grow < N) *(uint4*)&C[(size_t)grow * FDIM + col] = As4[c];
    }
}

// ---------------- fused pull-aggregate, one node per wave64, fp8 gather ----------------
// 4 row-groups of 16 lanes; batch-issues 4 independent 512-B gathers per round
// (all addresses known after one csr load) -> 4-deep memory pipeline per wave.

__launch_bounds__(256)
__global__ void k_aggregate(const unsigned char* __restrict__ xs8,
                            const int2* __restrict__ rowinfo,
                            const int* __restrict__ csr_src, const float* __restrict__ dinv,
                            const float* __restrict__ bias, ushort* __restrict__ out,
                            int N, int do_relu) {
    const int n = (blockIdx.x << 2) + (threadIdx.x >> 6);
    if (n >= N) return;
    const int l = threadIdx.x & 63;
    const int fl = l & 15;      // feature slot: features fl*8 .. fl*8+7
    const int grp = l >> 4;     // row group 0..3

    const uint2* xsr = (const uint2*)xs8;   // row r, slot fl at xsr[r*16 + fl]

    f32x2 acc[4] = {{0, 0}, {0, 0}, {0, 0}, {0, 0}};
    // self term: only group 0 accumulates it
    if (grp == 0) {
        uint2 sv = xsr[(size_t)n * 16 + fl];
        fp8x8_add(sv, acc);
    }

    const int2 ri = rowinfo[n];
    const int beg = ri.x;
    const int deg = ri.y;

    for (int base = 0; base < deg; base += 64) {
        const int m = min(64, deg - base);
        int idx = 0;
        if (l < m) idx = csr_src[beg + base + l];  // coalesced
        // groups process edges jb+u*4+grp; 4 loads issued before any accumulate
        for (int jb = 0; jb < m; jb += 16) {
            uint2 vb[4]; bool ok[4];
#pragma unroll
            for (int u = 0; u < 4; u++) {
                int j = jb + u * 4 + grp;
                ok[u] = (j < m);
                if (ok[u]) {
                    int s = __shfl(idx, j, 64);
                    vb[u] = xsr[(size_t)s * 16 + fl];
                }
            }
#pragma unroll
            for (int u = 0; u < 4; u++) if (ok[u]) fp8x8_add(vb[u], acc);
        }
    }

    // reduce the 4 row-groups (component-wise shuffles)
    float a[8] = {acc[0][0], acc[0][1], acc[1][0], acc[1][1],
                  acc[2][0], acc[2][1], acc[3][0], acc[3][1]};
#pragma unroll
    for (int k = 0; k < 8; k++) {
        a[k] += __shfl_xor(a[k], 16, 64);
        a[k] += __shfl_xor(a[k], 32, 64);
    }

    if (grp == 0) {
        const float d = dinv[n];
        const float4 b0 = ((const float4*)bias)[fl * 2];
        const float4 b1 = ((const float4*)bias)[fl * 2 + 1];
        const float bb[8] = {b0.x, b0.y, b0.z, b0.w, b1.x, b1.y, b1.z, b1.w};
        u16x8 o;
#pragma unroll
        for (int k = 0; k < 8; k++) {
            float v = d * a[k] + bb[k];
            if (do_relu) v = fmaxf(v, 0.f);
            o[k] = f2bf(v);
        }
        ((u16x8*)out)[(size_t)n * 16 + fl] = o;
    }
}

// ---------------- two-stage pool ----------------

#define POOL_NODES 128

__launch_bounds__(128)
__global__ void k_pool(const ushort* __restrict__ x3, const int* __restrict__ batch,
                       float* __restrict__ sums, int N) {
    const int t = threadIdx.x;
    const int n0 = blockIdx.x * POOL_NODES;
    if (n0 >= N) return;
    const int n1 = (n0 + POOL_NODES < N) ? n0 + POOL_NODES : N;

    float acc = 0.f;
    int cur = batch[n0];
    for (int n = n0; n < n1; n++) {
        int g = batch[n];
        if (g != cur) {
            atomicAdd(&sums[cur * FDIM + t], acc);
            acc = 0.f;
            cur = g;
        }
        acc += bf2f(x3[(size_t)n * FDIM + t]);
    }
    atomicAdd(&sums[cur * FDIM + t], acc);
}

// ---------------- per-graph mean + MLP + LayerNorm ----------------

__launch_bounds__(128)
__global__ void k_final(const float* __restrict__ sums, const int* __restrict__ batch, int N,
                        const float* __restrict__ Wm1, const float* __restrict__ bm1,
                        const float* __restrict__ Wm2, const float* __restrict__ bm2,
                        const float* __restrict__ ln_g, const float* __restrict__ ln_b,
                        float* __restrict__ out) {
    const int g = blockIdx.x;
    const int t = threadIdx.x;

    int lo = 0, hi = N;
    while (lo < hi) { int mid = (lo + hi) >> 1; if (batch[mid] < g) lo = mid + 1; else hi = mid; }
    int lo2 = lo, hi2 = N;
    while (lo2 < hi2) { int mid = (lo2 + hi2) >> 1; if (batch[mid] < g + 1) lo2 = mid + 1; else hi2 = mid; }
    float cnt = (float)(lo2 - lo);

    float gl = sums[g * FDIM + t] / fmaxf(cnt, 1.0f);

    __shared__ float gbuf[FDIM];
    __shared__ float hbuf[FDIM];
    __shared__ float wsum[4];
    gbuf[t] = gl;
    __syncthreads();

    float h = bm1[t];
#pragma unroll 8
    for (int k = 0; k < FDIM; k++) h += gbuf[k] * Wm1[k * FDIM + t];
    h = fmaxf(h, 0.f);
    hbuf[t] = h;
    __syncthreads();

    float y = bm2[t];
#pragma unroll 8
    for (int k = 0; k < FDIM; k++) y += hbuf[k] * Wm2[k * FDIM + t];

    float s = y, s2 = y * y;
#pragma unroll
    for (int off = 32; off > 0; off >>= 1) {
        s += __shfl_down(s, off, 64);
        s2 += __shfl_down(s2, off, 64);
    }
    if ((t & 63) == 0) { wsum[t >> 6] = s; wsum[2 + (t >> 6)] = s2; }
    __syncthreads();
    float sum = wsum[0] + wsum[1];
    float sumsq = wsum[2] + wsum[3];
    float mu = sum * (1.0f / FDIM);
    float var = sumsq * (1.0f / FDIM) - mu * mu;
    float r = rsqrtf(var + LN_EPS);
    out[g * FDIM + t] = (y - mu) * r * ln_g[t] + ln_b[t];
}

// ---------------- launch ----------------

extern "C" void kernel_launch(void* const* d_in, const int* in_sizes, int n_in,
                              void* d_out, int out_size, void* d_ws, size_t ws_size,
                              hipStream_t stream) {
    const float* x_in  = (const float*)d_in[0];
    const int*   eidx  = (const int*)d_in[1];
    const int*   batch = (const int*)d_in[2];
    const float* W1 = (const float*)d_in[3];
    const float* b1 = (const float*)d_in[4];
    const float* W2 = (const float*)d_in[5];
    const float* b2 = (const float*)d_in[6];
    const float* W3 = (const float*)d_in[7];
    const float* b3 = (const float*)d_in[8];
    const float* Wm1 = (const float*)d_in[9];
    const float* bm1 = (const float*)d_in[10];
    const float* Wm2 = (const float*)d_in[11];
    const float* bm2 = (const float*)d_in[12];
    const float* ln_g = (const float*)d_in[13];
    const float* ln_b = (const float*)d_in[14];
    float* out = (float*)d_out;

    const int N = in_sizes[0] / FDIM;   // 100000
    const int E = in_sizes[1] / 2;      // 1600000
    const int G = out_size / FDIM;      // 64

    const int* src = eidx;
    const int* dst = eidx + E;

    const int nbkt = (N + BKT_NODES - 1) >> NBKT_SHIFT;        // 98

    // workspace layout
    char* p = (char*)d_ws;
    unsigned* bktA = (unsigned*)p;    p += (size_t)nbkt * BKT_CAP * 4;   // 12.8 MB (packed)
    unsigned char* B0q = (unsigned char*)p; p += (size_t)N * FDIM;       // 12.8 MB (fp8 xs)
    ushort* B1h = (ushort*)p;         p += (size_t)N * FDIM * 2;         // 25.6 MB (bf16 agg)
    int* csr_src = (int*)p;           p += (size_t)nbkt * BKT_CAP * 4;   // 12.8 MB
    int2* rowinfo = (int2*)p;         p += (size_t)N * 8;
    float* dinv = (float*)p;          p += (size_t)N * 4;
    ushort* Wt = (ushort*)p;          p += 3 * 16384 * 2;
    float* gsums = (float*)p;         p += (size_t)G * FDIM * 4;         // zeroed
    int* bcur = (int*)p;              p += MAXBKT * 4;                   // zeroed

    const int TPB = 256;
    dim3 blk(TPB);
    dim3 gAgg((N + 3) / 4);
    dim3 gTile((N + 127) / 128);
    const int nEb = (E + 4095) / 4096;

    // ---- build (gsums and bcur adjacent -> one memset) ----
    k_prep_w<<<dim3(192), blk, 0, stream>>>(W1, W2, W3, Wt);
    hipMemsetAsync(gsums, 0, (size_t)G * FDIM * 4 + MAXBKT * 4, stream);
    k_bkt_scatter<<<dim3(nEb), blk, 0, stream>>>(src, dst, bcur, bktA, E, nbkt);
    k_build<<<dim3(nbkt), dim3(1024), 0, stream>>>(bktA, bcur, rowinfo, dinv, csr_src, N);

    // ---- layer 1 (fp32 input) ----
    k_gemm<true><<<gTile, blk, 0, stream>>>(x_in, Wt, dinv, B0q, N);
    k_aggregate<<<gAgg, blk, 0, stream>>>(B0q, rowinfo, csr_src, dinv, b1, B1h, N, 1);

    // ---- layer 2 ----
    k_gemm<false><<<gTile, blk, 0, stream>>>(B1h, Wt + 16384, dinv, B0q, N);
    k_aggregate<<<gAgg, blk, 0, stream>>>(B0q, rowinfo, csr_src, dinv, b2, B1h, N, 1);

    // ---- layer 3 (no relu) ----
    k_gemm<false><<<gTile, blk, 0, stream>>>(B1h, Wt + 32768, dinv, B0q, N);
    k_aggregate<<<gAgg, blk, 0, stream>>>(B0q, rowinfo, csr_src, dinv, b3, B1h, N, 0);

    // ---- pool + MLP + LN ----
    k_pool<<<dim3((N + POOL_NODES - 1) / POOL_NODES), dim3(FDIM), 0, stream>>>(B1h, batch, gsums, N);
    k_final<<<dim3(G), dim3(FDIM), 0, stream>>>(gsums, batch, N, Wm1, bm1, Wm2, bm2,
                                                ln_g, ln_b, out);
}

// Round 13
// 421.423 us; speedup vs baseline: 1.8711x; 1.0372x over previous
//
#include <hip/hip_runtime.h>

#define FDIM 128
#define LN_EPS 1e-5f
#define NBKT_SHIFT 10          // 1024 nodes per bucket
#define BKT_NODES 1024
#define MAXBKT 128             // supports N <= 131072 (src fits 17 bits packed)
#define CAP_SHIFT 15           // 32768 edge capacity per bucket (mean 16384, ~8 sigma)
#define BKT_CAP 32768

typedef short bf16x8 __attribute__((ext_vector_type(8)));
typedef float f32x4 __attribute__((ext_vector_type(4)));
typedef float f32x2 __attribute__((ext_vector_type(2)));
typedef ushort u16x8 __attribute__((ext_vector_type(8)));
typedef unsigned long long u64;
typedef long long i64;

static __device__ __forceinline__ ushort f2bf(float f) {
    union { float f; unsigned u; } v; v.f = f;
    unsigned r = v.u + 0x7FFFu + ((v.u >> 16) & 1u);  // RNE
    return (ushort)(r >> 16);
}
static __device__ __forceinline__ float bf2f(ushort h) {
    union { unsigned u; float f; } v; v.u = ((unsigned)h) << 16;
    return v.f;
}
// fp8 e4m3 (OCP on gfx950) encode/decode via HW converts
static __device__ __forceinline__ unsigned char f2fp8(float f) {
    return (unsigned char)__builtin_amdgcn_cvt_pk_fp8_f32(f, f, 0u, false);
}
static __device__ __forceinline__ float fp8tof(unsigned char b) {
    f32x2 p = __builtin_amdgcn_cvt_pk_f32_fp8((unsigned)b, false);
    return p[0];
}
static __device__ __forceinline__ void fp8x8_add(uint2 w, f32x2* acc) {
    acc[0] += __builtin_amdgcn_cvt_pk_f32_fp8(w.x, false);
    acc[1] += __builtin_amdgcn_cvt_pk_f32_fp8(w.x, true);
    acc[2] += __builtin_amdgcn_cvt_pk_f32_fp8(w.y, false);
    acc[3] += __builtin_amdgcn_cvt_pk_f32_fp8(w.y, true);
}

// ---------------- bucketed edge scatter (fixed-capacity buckets) ----------------
// 4096 edges/block. Packs (src,local_dst) into one u32: src<<10 | (dst & 1023).

__launch_bounds__(256)
__global__ void k_bkt_scatter(const int* __restrict__ src, const int* __restrict__ dst,
                              int* __restrict__ bcur, unsigned* __restrict__ bktA,
                              int E, int nbkt) {
    __shared__ int h[2][MAXBKT], lbase[2][MAXBKT], lcur[2][MAXBKT];
    const int t = threadIdx.x;
    const int half = t >> 7;
    for (int i = t; i < 2 * MAXBKT; i += 256) ((int*)h)[i] = 0;
    __syncthreads();
    const int E4 = E >> 2;   // E multiple of 4
    const int4* s4p = (const int4*)src;
    const int4* d4p = (const int4*)dst;
    int4 sv[4], dv[4]; bool ok[4];
#pragma unroll
    for (int r = 0; r < 4; r++) {
        int i4 = blockIdx.x * 1024 + r * 256 + t;
        ok[r] = (i4 < E4);
        if (ok[r]) {
            sv[r] = s4p[i4]; dv[r] = d4p[i4];
            atomicAdd(&h[half][dv[r].x >> NBKT_SHIFT], 1);
            atomicAdd(&h[half][dv[r].y >> NBKT_SHIFT], 1);
            atomicAdd(&h[half][dv[r].z >> NBKT_SHIFT], 1);
            atomicAdd(&h[half][dv[r].w >> NBKT_SHIFT], 1);
        }
    }
    __syncthreads();
    for (int i = t; i < 2 * nbkt; i += 256) {
        const int hh = (i >= nbkt) ? 1 : 0;
        const int b = hh ? (i - nbkt) : i;
        const int c = h[hh][b];
        lbase[hh][b] = c ? ((b << CAP_SHIFT) + atomicAdd(&bcur[b], c)) : 0;
        lcur[hh][b] = 0;
    }
    __syncthreads();
#pragma unroll
    for (int r = 0; r < 4; r++) {
        if (!ok[r]) continue;
        int ss[4] = {sv[r].x, sv[r].y, sv[r].z, sv[r].w};
        int dd[4] = {dv[r].x, dv[r].y, dv[r].z, dv[r].w};
#pragma unroll
        for (int j = 0; j < 4; j++) {
            int b = dd[j] >> NBKT_SHIFT;
            int p = atomicAdd(&lcur[half][b], 1);
            bktA[(size_t)lbase[half][b] + p] =
                ((unsigned)ss[j] << NBKT_SHIFT) | (unsigned)(dd[j] & (BKT_NODES - 1));
        }
    }
}

// merged per-bucket: degree count -> wave-level scan -> rowinfo/dinv -> CSR fill

__launch_bounds__(1024)
__global__ void k_build(const unsigned* __restrict__ bktA, const int* __restrict__ bcur,
                        int2* __restrict__ rowinfo, float* __restrict__ dinv,
                        int* __restrict__ csr_src, int N) {
    __shared__ int cnt[BKT_NODES];
    __shared__ int cur[BKT_NODES];
    __shared__ int wpart[16], wbase[16];
    const int t = threadIdx.x;
    const int b = blockIdx.x;
    const int nb = b << NBKT_SHIFT;
    cnt[t] = 0;
    __syncthreads();
    const int beg = b << CAP_SHIFT;
    const int end = beg + bcur[b];
    for (int i = beg + t; i < end; i += 1024)
        atomicAdd(&cnt[bktA[i] & (BKT_NODES - 1)], 1);
    __syncthreads();
    const int lane = t & 63, wv = t >> 6;
    const int my = cnt[t];
    int x = my;
#pragma unroll
    for (int off = 1; off < 64; off <<= 1) {
        int y = __shfl_up(x, off, 64);
        if (lane >= off) x += y;
    }
    if (lane == 63) wpart[wv] = x;
    __syncthreads();
    if (t == 0) {
        int s = 0;
        for (int w = 0; w < 16; w++) { int tmp = wpart[w]; wbase[w] = s; s += tmp; }
    }
    __syncthreads();
    const int incl = x + wbase[wv];
    const int rbeg = beg + incl - my;   // exclusive start within padded CSR
    cur[t] = rbeg;
    const int n = nb + t;
    if (n < N) {
        rowinfo[n] = make_int2(rbeg, my);
        dinv[n] = rsqrtf((float)(my + 1));  // +1 self-loop
    }
    __syncthreads();
    for (int i = beg + t; i < end; i += 1024) {
        unsigned pr = bktA[i];
        int d = pr & (BKT_NODES - 1);
        int p = atomicAdd(&cur[d], 1);
        csr_src[p] = (int)(pr >> NBKT_SHIFT);
    }
}

// ---------------- W prep: layer0 -> bf16 Wt_b[n][k]; layers 1,2 -> fp8 Wt8 ----------------
// Also zeroes gsums and bcur (replaces a memset dispatch; runs before scatter).

__global__ void k_prep_w(const float* __restrict__ Wa, const float* __restrict__ Wb,
                         const float* __restrict__ Wc, ushort* __restrict__ Wt_b,
                         unsigned char* __restrict__ Wt8, float* __restrict__ gsums,
                         int* __restrict__ bcur) {
    int idx = blockIdx.x * 256 + threadIdx.x;  // 192*256 = 49152 = 3*16384
    int layer = idx >> 14;
    int r = idx & 16383;
    int nn = r >> 7, kk = r & 127;
    if (layer == 0) {
        Wt_b[r] = f2bf(Wa[kk * 128 + nn]);
    } else {
        const float* W = (layer == 1) ? Wb : Wc;
        Wt8[(size_t)(layer - 1) * 16384 + r] = f2fp8(W[kk * 128 + nn]);
    }
    if (idx < 8192) gsums[idx] = 0.f;
    if (idx < MAXBKT) bcur[idx] = 0;
}

// ---------------- layer-1 MFMA GEMM (bf16): xs(fp8) = dinv .* (X_f32 @ W) ----------------

__launch_bounds__(256)
__global__ void k_gemm_f32(const float* __restrict__ X, const ushort* __restrict__ Wt,
                           const float* __restrict__ dinv, unsigned char* __restrict__ C,
                           int N) {
    __shared__ __align__(16) ushort As[128][136];
    __shared__ ushort Ws[128][136];
    const int t = threadIdx.x;
    const int row0 = blockIdx.x * 128;

#pragma unroll
    for (int i = 0; i < 8; i++) {
        int c = t + i * 256;
        int r = c >> 4, c8 = (c & 15) * 8;
        *(bf16x8*)&Ws[r][c8] = *(const bf16x8*)&Wt[r * 128 + c8];
    }
#pragma unroll
    for (int i = 0; i < 8; i++) {
        int c = t + i * 256;
        int r = c >> 4, c8 = (c & 15) * 8;
        int row = row0 + r;
        bf16x8 pk = {0, 0, 0, 0, 0, 0, 0, 0};
        if (row < N) {
            const float* sp = X + (size_t)row * FDIM + c8;
            float4 u0 = *(const float4*)(sp);
            float4 u1 = *(const float4*)(sp + 4);
            pk[0] = (short)f2bf(u0.x); pk[1] = (short)f2bf(u0.y);
            pk[2] = (short)f2bf(u0.z); pk[3] = (short)f2bf(u0.w);
            pk[4] = (short)f2bf(u1.x); pk[5] = (short)f2bf(u1.y);
            pk[6] = (short)f2bf(u1.z); pk[7] = (short)f2bf(u1.w);
        }
        *(bf16x8*)&As[r][c8] = pk;
    }
    __syncthreads();

    const int w = t >> 6, l = t & 63;
    const int m = l & 15, q = l >> 4;
    const int r0 = w * 32;

    bf16x8 a0[4], a1[4];
#pragma unroll
    for (int ks = 0; ks < 4; ks++) {
        a0[ks] = *(const bf16x8*)&As[r0 + m][ks * 32 + q * 8];
        a1[ks] = *(const bf16x8*)&As[r0 + 16 + m][ks * 32 + q * 8];
    }

    f32x4 acc0[8], acc1[8];
#pragma unroll
    for (int ct = 0; ct < 8; ct++) { acc0[ct] = {0, 0, 0, 0}; acc1[ct] = {0, 0, 0, 0}; }

#pragma unroll
    for (int ct = 0; ct < 8; ct++) {
#pragma unroll
        for (int ks = 0; ks < 4; ks++) {
            bf16x8 b = *(const bf16x8*)&Ws[ct * 16 + m][ks * 32 + q * 8];
            acc0[ct] = __builtin_amdgcn_mfma_f32_16x16x32_bf16(a0[ks], b, acc0[ct], 0, 0, 0);
            acc1[ct] = __builtin_amdgcn_mfma_f32_16x16x32_bf16(a1[ks], b, acc1[ct], 0, 0, 0);
        }
    }

    float dv0[4], dv1[4];
#pragma unroll
    for (int r = 0; r < 4; r++) {
        int row = row0 + r0 + q * 4 + r;
        dv0[r] = (row < N) ? dinv[row] : 0.f;
        dv1[r] = (row + 16 < N) ? dinv[row + 16] : 0.f;
    }

    // stage fp8 tile into LDS (reuse As), then coalesced 16-B stores
    __syncthreads();
    char* Ab = (char*)&As[0][0];
#pragma unroll
    for (int ct = 0; ct < 8; ct++) {
#pragma unroll
        for (int r = 0; r < 4; r++) {
            int rl = r0 + q * 4 + r;
            Ab[rl * 128 + ct * 16 + m] = (char)f2fp8(acc0[ct][r] * dv0[r]);
            Ab[(rl + 16) * 128 + ct * 16 + m] = (char)f2fp8(acc1[ct][r] * dv1[r]);
        }
    }
    __syncthreads();
    const uint4* As4 = (const uint4*)Ab;
#pragma unroll
    for (int i = 0; i < 4; i++) {
        int c = t + i * 256;
        int row = c >> 3;
        int col = (c & 7) * 16;
        int grow = row0 + row;
        if (grow < N) *(uint4*)&C[(size_t)grow * FDIM + col] = As4[c];
    }
}

// ---------------- layers 2/3 MFMA GEMM (fp8 x fp8): xs(fp8) = dinv .* (A_fp8 @ W_fp8) ----

__launch_bounds__(256)
__global__ void k_gemm_fp8(const unsigned char* __restrict__ X,
                           const unsigned char* __restrict__ W8,
                           const float* __restrict__ dinv, unsigned char* __restrict__ C,
                           int N) {
    __shared__ __align__(16) unsigned char As[128][144];
    __shared__ __align__(16) unsigned char Ws[128][144];
    const int t = threadIdx.x;
    const int row0 = blockIdx.x * 128;

#pragma unroll
    for (int i = 0; i < 4; i++) {
        int c = t + i * 256;          // 1024 chunks of 16 B
        int r = c >> 3, col = (c & 7) * 16;
        *(uint4*)&Ws[r][col] = *(const uint4*)&W8[r * 128 + col];
        int row = row0 + r;
        uint4 v = {0, 0, 0, 0};
        if (row < N) v = *(const uint4*)&X[(size_t)row * FDIM + col];
        *(uint4*)&As[r][col] = v;
    }
    __syncthreads();

    const int w = t >> 6, l = t & 63;
    const int m = l & 15, q = l >> 4;
    const int r0 = w * 32;

    i64 a0[4], a1[4];
#pragma unroll
    for (int ks = 0; ks < 4; ks++) {
        a0[ks] = *(const i64*)&As[r0 + m][ks * 32 + q * 8];
        a1[ks] = *(const i64*)&As[r0 + 16 + m][ks * 32 + q * 8];
    }

    f32x4 acc0[8], acc1[8];
#pragma unroll
    for (int ct = 0; ct < 8; ct++) { acc0[ct] = {0, 0, 0, 0}; acc1[ct] = {0, 0, 0, 0}; }

#pragma unroll
    for (int ct = 0; ct < 8; ct++) {
#pragma unroll
        for (int ks = 0; ks < 4; ks++) {
            i64 b = *(const i64*)&Ws[ct * 16 + m][ks * 32 + q * 8];
            acc0[ct] = __builtin_amdgcn_mfma_f32_16x16x32_fp8_fp8(a0[ks], b, acc0[ct], 0, 0, 0);
            acc1[ct] = __builtin_amdgcn_mfma_f32_16x16x32_fp8_fp8(a1[ks], b, acc1[ct], 0, 0, 0);
        }
    }

    float dv0[4], dv1[4];
#pragma unroll
    for (int r = 0; r < 4; r++) {
        int row = row0 + r0 + q * 4 + r;
        dv0[r] = (row < N) ? dinv[row] : 0.f;
        dv1[r] = (row + 16 < N) ? dinv[row + 16] : 0.f;
    }

    __syncthreads();
    char* Ab = (char*)&As[0][0];
#pragma unroll
    for (int ct = 0; ct < 8; ct++) {
#pragma unroll
        for (int r = 0; r < 4; r++) {
            int rl = r0 + q * 4 + r;
            Ab[rl * 128 + ct * 16 + m] = (char)f2fp8(acc0[ct][r] * dv0[r]);
            Ab[(rl + 16) * 128 + ct * 16 + m] = (char)f2fp8(acc1[ct][r] * dv1[r]);
        }
    }
    __syncthreads();
    const uint4* As4 = (const uint4*)Ab;
#pragma unroll
    for (int i = 0; i < 4; i++) {
        int c = t + i * 256;
        int row = c >> 3;
        int col = (c & 7) * 16;
        int grow = row0 + row;
        if (grow < N) *(uint4*)&C[(size_t)grow * FDIM + col] = As4[c];
    }
}

// ---------------- fused pull-aggregate, one node per wave64, fp8 in / fp8 out ----------------
// R11 inner loop (proven): 4 row-groups x 16 lanes, 512-B gathers, 1-deep prefetch.

__launch_bounds__(256)
__global__ void k_aggregate(const unsigned char* __restrict__ xs8,
                            const int2* __restrict__ rowinfo,
                            const int* __restrict__ csr_src, const float* __restrict__ dinv,
                            const float* __restrict__ bias, unsigned char* __restrict__ out,
                            int N, int do_relu) {
    const int n = (blockIdx.x << 2) + (threadIdx.x >> 6);
    if (n >= N) return;
    const int l = threadIdx.x & 63;
    const int fl = l & 15;      // feature slot: features fl*8 .. fl*8+7
    const int grp = l >> 4;     // row group 0..3

    const uint2* xsr = (const uint2*)xs8;   // row r, slot fl at xsr[r*16 + fl]

    f32x2 acc[4] = {{0, 0}, {0, 0}, {0, 0}, {0, 0}};
    if (grp == 0) {
        uint2 sv = xsr[(size_t)n * 16 + fl];
        fp8x8_add(sv, acc);
    }

    const int2 ri = rowinfo[n];
    const int beg = ri.x;
    const int deg = ri.y;

    for (int base = 0; base < deg; base += 64) {
        const int m = min(64, deg - base);
        int idx = 0;
        if (l < m) idx = csr_src[beg + base + l];  // coalesced
        int j = grp;
        if (j < m) {
            int s = __shfl(idx, j, 64);
            uint2 v = xsr[(size_t)s * 16 + fl];
#pragma unroll 2
            for (j += 4; j < m; j += 4) {
                int s2 = __shfl(idx, j, 64);
                uint2 v2 = xsr[(size_t)s2 * 16 + fl];   // prefetch next
                fp8x8_add(v, acc);
                v = v2;
            }
            fp8x8_add(v, acc);
        }
    }

    float a[8] = {acc[0][0], acc[0][1], acc[1][0], acc[1][1],
                  acc[2][0], acc[2][1], acc[3][0], acc[3][1]};
#pragma unroll
    for (int k = 0; k < 8; k++) {
        a[k] += __shfl_xor(a[k], 16, 64);
        a[k] += __shfl_xor(a[k], 32, 64);
    }

    if (grp == 0) {
        const float d = dinv[n];
        const float4 b0 = ((const float4*)bias)[fl * 2];
        const float4 b1 = ((const float4*)bias)[fl * 2 + 1];
        const float bb[8] = {b0.x, b0.y, b0.z, b0.w, b1.x, b1.y, b1.z, b1.w};
        float v[8];
#pragma unroll
        for (int k = 0; k < 8; k++) {
            v[k] = d * a[k] + bb[k];
            if (do_relu) v[k] = fmaxf(v[k], 0.f);
        }
        uint2 o;
        unsigned d0 = __builtin_amdgcn_cvt_pk_fp8_f32(v[0], v[1], 0u, false);
        o.x = __builtin_amdgcn_cvt_pk_fp8_f32(v[2], v[3], d0, true);
        unsigned d1 = __builtin_amdgcn_cvt_pk_fp8_f32(v[4], v[5], 0u, false);
        o.y = __builtin_amdgcn_cvt_pk_fp8_f32(v[6], v[7], d1, true);
        ((uint2*)out)[(size_t)n * 16 + fl] = o;
    }
}

// ---------------- two-stage pool (fp8 input) ----------------

#define POOL_NODES 128

__launch_bounds__(128)
__global__ void k_pool(const unsigned char* __restrict__ x3, const int* __restrict__ batch,
                       float* __restrict__ sums, int N) {
    const int t = threadIdx.x;
    const int n0 = blockIdx.x * POOL_NODES;
    if (n0 >= N) return;
    const int n1 = (n0 + POOL_NODES < N) ? n0 + POOL_NODES : N;

    float acc = 0.f;
    int cur = batch[n0];
    for (int n = n0; n < n1; n++) {
        int g = batch[n];
        if (g != cur) {
            atomicAdd(&sums[cur * FDIM + t], acc);
            acc = 0.f;
            cur = g;
        }
        acc += fp8tof(x3[(size_t)n * FDIM + t]);
    }
    atomicAdd(&sums[cur * FDIM + t], acc);
}

// ---------------- per-graph mean + MLP + LayerNorm ----------------

__launch_bounds__(128)
__global__ void k_final(const float* __restrict__ sums, const int* __restrict__ batch, int N,
                        const float* __restrict__ Wm1, const float* __restrict__ bm1,
                        const float* __restrict__ Wm2, const float* __restrict__ bm2,
                        const float* __restrict__ ln_g, const float* __restrict__ ln_b,
                        float* __restrict__ out) {
    const int g = blockIdx.x;
    const int t = threadIdx.x;

    int lo = 0, hi = N;
    while (lo < hi) { int mid = (lo + hi) >> 1; if (batch[mid] < g) lo = mid + 1; else hi = mid; }
    int lo2 = lo, hi2 = N;
    while (lo2 < hi2) { int mid = (lo2 + hi2) >> 1; if (batch[mid] < g + 1) lo2 = mid + 1; else hi2 = mid; }
    float cnt = (float)(lo2 - lo);

    float gl = sums[g * FDIM + t] / fmaxf(cnt, 1.0f);

    __shared__ float gbuf[FDIM];
    __shared__ float hbuf[FDIM];
    __shared__ float wsum[4];
    gbuf[t] = gl;
    __syncthreads();

    float h = bm1[t];
#pragma unroll 8
    for (int k = 0; k < FDIM; k++) h += gbuf[k] * Wm1[k * FDIM + t];
    h = fmaxf(h, 0.f);
    hbuf[t] = h;
    __syncthreads();

    float y = bm2[t];
#pragma unroll 8
    for (int k = 0; k < FDIM; k++) y += hbuf[k] * Wm2[k * FDIM + t];

    float s = y, s2 = y * y;
#pragma unroll
    for (int off = 32; off > 0; off >>= 1) {
        s += __shfl_down(s, off, 64);
        s2 += __shfl_down(s2, off, 64);
    }
    if ((t & 63) == 0) { wsum[t >> 6] = s; wsum[2 + (t >> 6)] = s2; }
    __syncthreads();
    float sum = wsum[0] + wsum[1];
    float sumsq = wsum[2] + wsum[3];
    float mu = sum * (1.0f / FDIM);
    float var = sumsq * (1.0f / FDIM) - mu * mu;
    float r = rsqrtf(var + LN_EPS);
    out[g * FDIM + t] = (y - mu) * r * ln_g[t] + ln_b[t];
}

// ---------------- launch ----------------

extern "C" void kernel_launch(void* const* d_in, const int* in_sizes, int n_in,
                              void* d_out, int out_size, void* d_ws, size_t ws_size,
                              hipStream_t stream) {
    const float* x_in  = (const float*)d_in[0];
    const int*   eidx  = (const int*)d_in[1];
    const int*   batch = (const int*)d_in[2];
    const float* W1 = (const float*)d_in[3];
    const float* b1 = (const float*)d_in[4];
    const float* W2 = (const float*)d_in[5];
    const float* b2 = (const float*)d_in[6];
    const float* W3 = (const float*)d_in[7];
    const float* b3 = (const float*)d_in[8];
    const float* Wm1 = (const float*)d_in[9];
    const float* bm1 = (const float*)d_in[10];
    const float* Wm2 = (const float*)d_in[11];
    const float* bm2 = (const float*)d_in[12];
    const float* ln_g = (const float*)d_in[13];
    const float* ln_b = (const float*)d_in[14];
    float* out = (float*)d_out;

    const int N = in_sizes[0] / FDIM;   // 100000
    const int E = in_sizes[1] / 2;      // 1600000
    const int G = out_size / FDIM;      // 64

    const int* src = eidx;
    const int* dst = eidx + E;

    const int nbkt = (N + BKT_NODES - 1) >> NBKT_SHIFT;        // 98

    // workspace layout
    char* p = (char*)d_ws;
    unsigned* bktA = (unsigned*)p;    p += (size_t)nbkt * BKT_CAP * 4;   // 12.8 MB (packed)
    unsigned char* B0q = (unsigned char*)p; p += (size_t)N * FDIM;       // 12.8 MB (fp8 xs)
    unsigned char* B1q = (unsigned char*)p; p += (size_t)N * FDIM;       // 12.8 MB (fp8 agg)
    int* csr_src = (int*)p;           p += (size_t)nbkt * BKT_CAP * 4;   // 12.8 MB
    int2* rowinfo = (int2*)p;         p += (size_t)N * 8;
    float* dinv = (float*)p;          p += (size_t)N * 4;
    ushort* Wt_b = (ushort*)p;        p += 16384 * 2;
    unsigned char* Wt8 = (unsigned char*)p; p += 2 * 16384;
    float* gsums = (float*)p;         p += (size_t)G * FDIM * 4;
    int* bcur = (int*)p;              p += MAXBKT * 4;

    const int TPB = 256;
    dim3 blk(TPB);
    dim3 gAgg((N + 3) / 4);
    dim3 gTile((N + 127) / 128);
    const int nEb = (E + 4095) / 4096;

    // ---- prep (also zeroes gsums/bcur) + build ----
    k_prep_w<<<dim3(192), blk, 0, stream>>>(W1, W2, W3, Wt_b, Wt8, gsums, bcur);
    k_bkt_scatter<<<dim3(nEb), blk, 0, stream>>>(src, dst, bcur, bktA, E, nbkt);
    k_build<<<dim3(nbkt), dim3(1024), 0, stream>>>(bktA, bcur, rowinfo, dinv, csr_src, N);

    // ---- layer 1 (fp32 input, bf16 MFMA) ----
    k_gemm_f32<<<gTile, blk, 0, stream>>>(x_in, Wt_b, dinv, B0q, N);
    k_aggregate<<<gAgg, blk, 0, stream>>>(B0q, rowinfo, csr_src, dinv, b1, B1q, N, 1);

    // ---- layer 2 (fp8 MFMA) ----
    k_gemm_fp8<<<gTile, blk, 0, stream>>>(B1q, Wt8, dinv, B0q, N);
    k_aggregate<<<gAgg, blk, 0, stream>>>(B0q, rowinfo, csr_src, dinv, b2, B1q, N, 1);

    // ---- layer 3 (fp8 MFMA, no relu) ----
    k_gemm_fp8<<<gTile, blk, 0, stream>>>(B1q, Wt8 + 16384, dinv, B0q, N);
    k_aggregate<<<gAgg, blk, 0, stream>>>(B0q, rowinfo, csr_src, dinv, b3, B1q, N, 0);

    // ---- pool + MLP + LN ----
    k_pool<<<dim3((N + POOL_NODES - 1) / POOL_NODES), dim3(FDIM), 0, stream>>>(B1q, batch, gsums, N);
    k_final<<<dim3(G), dim3(FDIM), 0, stream>>>(gsums, batch, N, Wm1, bm1, Wm2, bm2,
                                                ln_g, ln_b, out);
}